// Round 2
// baseline (656.981 us; speedup 1.0000x reference)
//
#include <hip/hip_runtime.h>
#include <hip/hip_bf16.h>

// PhraseDecoderLayer: B=4,S=1024,D=1024,H=16,HD=64,DFF=4096,MEM=256.
// Round 11: identical to round 10 (bench was an infra flake — container
// acquisition failed twice; no counter or correctness evidence).
// gemm128 = m97 structure: single linear LDS buffer [128][32] (no padding:
// global_load_lds writes wave-uniform base + lane*16, staging map tid*16 is
// exactly that), 4x global_load_lds width=16 per K-step, 2 barriers per
// K-step. LDS 40KB->16KB (occupancy ceiling 2-3 -> 4+ blocks/CU).
// Attention / kv GEMMs / LN / canon unchanged from passing rounds.

using bf16 = __hip_bfloat16;
typedef __bf16 bf16x8 __attribute__((ext_vector_type(8)));
typedef float f32x4 __attribute__((ext_vector_type(4)));

static constexpr int Bn = 4, Ssz = 1024, Dm = 1024, Hh = 16, HDd = 64, DFFn = 4096, MEMn = 256;

__device__ inline float bf2f(bf16 x) { return __bfloat162float(x); }
__device__ inline bf16 f2bf(float x) { return __float2bfloat16(x); }

// async global->LDS, 16B per lane. LDS dest must be linear in tid (wave-uniform
// base + lane*16); caller guarantees &lds byte offset == tid*16 within segment.
__device__ __forceinline__ void gload16(const bf16* g, bf16* l) {
  __builtin_amdgcn_global_load_lds(
      (const __attribute__((address_space(1))) void*)g,
      (__attribute__((address_space(3))) void*)l, 16, 0, 0);
}

// ---------------- dtype detect ----------------
__global__ void detect_kernel(const unsigned* __restrict__ cosw, int* __restrict__ flag) {
  if (threadIdx.x == 0) *flag = (cosw[0] == 0x3F800000u) ? 1 : 0;
}

// ---------------- fused canonicalize: all inputs -> bf16 (+f32 resid for seg0) ----
struct CanonArgs {
  const void* src[23];
  void* dst[23];
  int n[23];  // element count (0 = skip); all counts divisible by 4
};
__global__ __launch_bounds__(256) void canon_all(CanonArgs a, float* __restrict__ resid,
                                                 const int* __restrict__ flagp) {
  const int seg = blockIdx.y;
  const int n4 = a.n[seg] >> 2;
  if (n4 == 0) return;
  const int fl = *flagp;  // wave-uniform
  if (fl) {
    const float4* s = (const float4*)a.src[seg];
    bf16* d = (bf16*)a.dst[seg];
    for (int i = blockIdx.x * 256 + threadIdx.x; i < n4; i += gridDim.x * 256) {
      float4 v = s[i];
      bf16 t[4] = {f2bf(v.x), f2bf(v.y), f2bf(v.z), f2bf(v.w)};
      *reinterpret_cast<unsigned long long*>(d + i * 4) =
          *reinterpret_cast<unsigned long long*>(t);
      if (seg == 0) *reinterpret_cast<float4*>(resid + i * 4) = v;
    }
  } else {
    const unsigned long long* s = (const unsigned long long*)a.src[seg];
    unsigned long long* d = (unsigned long long*)a.dst[seg];
    for (int i = blockIdx.x * 256 + threadIdx.x; i < n4; i += gridDim.x * 256) {
      unsigned long long v = s[i];
      d[i] = v;
      if (seg == 0) {
        const unsigned short* u = reinterpret_cast<const unsigned short*>(&v);
        float4 f;
        f.x = __uint_as_float(((unsigned)u[0]) << 16);
        f.y = __uint_as_float(((unsigned)u[1]) << 16);
        f.z = __uint_as_float(((unsigned)u[2]) << 16);
        f.w = __uint_as_float(((unsigned)u[3]) << 16);
        *reinterpret_cast<float4*>(resid + i * 4) = f;
      }
    }
  }
}

// ---------------- LayerNorm (rows of 1024, fp32 in, bf16 out) ----------------
__global__ __launch_bounds__(256) void ln_kernel(const float* __restrict__ x,
                                                 const bf16* __restrict__ g,
                                                 const bf16* __restrict__ bb,
                                                 bf16* __restrict__ y) {
  const int row = blockIdx.x;
  const float* xr = x + (size_t)row * Dm;
  const int i0 = threadIdx.x * 4;
  float4 v = *reinterpret_cast<const float4*>(xr + i0);
  float s = v.x + v.y + v.z + v.w;
  float ss = v.x * v.x + v.y * v.y + v.z * v.z + v.w * v.w;
#pragma unroll
  for (int o = 32; o > 0; o >>= 1) {
    s += __shfl_down(s, o);
    ss += __shfl_down(ss, o);
  }
  __shared__ float shs[4], shss[4];
  const int wave = threadIdx.x >> 6, lane = threadIdx.x & 63;
  if (lane == 0) { shs[wave] = s; shss[wave] = ss; }
  __syncthreads();
  s = shs[0] + shs[1] + shs[2] + shs[3];
  ss = shss[0] + shss[1] + shss[2] + shss[3];
  const float mu = s * (1.0f / Dm);
  const float var = fmaxf(ss * (1.0f / Dm) - mu * mu, 0.0f);
  const float rs = rsqrtf(var + 1e-5f);
  bf16* yr = y + (size_t)row * Dm + i0;
  float vv[4] = {v.x, v.y, v.z, v.w};
#pragma unroll
  for (int j = 0; j < 4; ++j)
    yr[j] = f2bf((vv[j] - mu) * rs * bf2f(g[i0 + j]) + bf2f(bb[i0 + j]));
}

// ---------------- GEMM 64x64 (round-2 verified; used for M=1024 kv) --------
__global__ __launch_bounds__(256) void gemm_bt(
    const bf16* __restrict__ A, const bf16* __restrict__ W,
    const bf16* __restrict__ bias, bf16* __restrict__ outB, float* __restrict__ outF,
    const float* __restrict__ residIn, float* __restrict__ residOut,
    const int* __restrict__ flagp, int M, int N, int K, int epi) {
  __shared__ bf16 As[64][40];
  __shared__ bf16 Ws[64][40];
  const int tid = threadIdx.x;
  const int m0 = blockIdx.x * 64, n0 = blockIdx.y * 64;
  const int wave = tid >> 6, lane = tid & 63;
  const int wm = wave >> 1, wn = wave & 1;
  const int quad = lane >> 4, m16 = lane & 15;
  const int lr = tid >> 2, lc = (tid & 3) * 8;

  f32x4 acc[2][2] = {};

  const bf16* Ap = A + (size_t)(m0 + lr) * K + lc;
  const bf16* Wp = W + (size_t)(n0 + lr) * K + lc;
  for (int k0 = 0; k0 < K; k0 += 32) {
    float4 av = *reinterpret_cast<const float4*>(Ap + k0);
    float4 wv = *reinterpret_cast<const float4*>(Wp + k0);
    *reinterpret_cast<float4*>(&As[lr][lc]) = av;
    *reinterpret_cast<float4*>(&Ws[lr][lc]) = wv;
    __syncthreads();
    bf16x8 aF[2], bF[2];
#pragma unroll
    for (int t = 0; t < 2; ++t) {
      aF[t] = *reinterpret_cast<const bf16x8*>(&As[wm * 32 + t * 16 + m16][quad * 8]);
      bF[t] = *reinterpret_cast<const bf16x8*>(&Ws[wn * 32 + t * 16 + m16][quad * 8]);
    }
#pragma unroll
    for (int mt = 0; mt < 2; ++mt)
#pragma unroll
      for (int nt = 0; nt < 2; ++nt)
        acc[mt][nt] = __builtin_amdgcn_mfma_f32_16x16x32_bf16(aF[mt], bF[nt], acc[mt][nt], 0, 0, 0);
    __syncthreads();
  }
  const int fl = (epi == 3) ? *flagp : 0;
#pragma unroll
  for (int mt = 0; mt < 2; ++mt) {
#pragma unroll
    for (int nt = 0; nt < 2; ++nt) {
      const int col = n0 + wn * 32 + nt * 16 + m16;
      const float bv = bf2f(bias[col]);
#pragma unroll
      for (int r = 0; r < 4; ++r) {
        const int row = m0 + wm * 32 + mt * 16 + quad * 4 + r;
        const size_t idx = (size_t)row * N + col;
        float v = acc[mt][nt][r] + bv;
        if (epi == 0) {
          outB[idx] = f2bf(v);
        } else if (epi == 1) {
          outB[idx] = f2bf(0.5f * v * (1.0f + erff(v * 0.70710678118654752f)));
        } else if (epi == 2) {
          residOut[idx] = residIn[idx] + v;
        } else {
          const float rr = residIn[idx] + v;
          if (fl) outF[idx] = rr; else outB[idx] = f2bf(rr);
        }
      }
    }
  }
}

// ---------------- GEMM 128x128: m97 structure ----------------
// Single linear LDS buffer [128][32] (byte offset of thread t's 16B segment is
// exactly t*16 -> wave-uniform base + lane*16, the HW staging pattern).
// Per K-step: 4x global_load_lds(16B) -> barrier (compiler drains vmcnt) ->
// 8x ds_read_b128 frags -> 16 MFMA -> barrier.
__global__ __launch_bounds__(256) void gemm128(
    const bf16* __restrict__ A, const bf16* __restrict__ W,
    const bf16* __restrict__ bias, bf16* __restrict__ outB, float* __restrict__ outF,
    const float* __restrict__ residIn, float* __restrict__ residOut,
    const int* __restrict__ flagp, int M, int N, int K, int epi) {
  __shared__ bf16 As[128][32];
  __shared__ bf16 Ws[128][32];
  const int tid = threadIdx.x;
  const int wave = tid >> 6, lane = tid & 63;
  const int wm = wave >> 1, wn = wave & 1;
  const int quad = lane >> 4, m16 = lane & 15;
  const int m0 = blockIdx.x * 128, n0 = blockIdx.y * 128;

  const int sr = tid >> 2;       // 0..63 (tile row)
  const int sc = (tid & 3) * 8;  // 0,8,16,24 (k-col)
  const bf16* Ap = A + (size_t)(m0 + sr) * K + sc;
  const bf16* Wp = W + (size_t)(n0 + sr) * K + sc;
  const size_t rowOff = (size_t)64 * K;

  f32x4 acc[4][4] = {};

  for (int k0 = 0; k0 < K; k0 += 32) {
    gload16(Ap + k0, &As[sr][sc]);
    gload16(Ap + rowOff + k0, &As[64 + sr][sc]);
    gload16(Wp + k0, &Ws[sr][sc]);
    gload16(Wp + rowOff + k0, &Ws[64 + sr][sc]);
    __syncthreads();
    bf16x8 aF[4], bF[4];
#pragma unroll
    for (int t = 0; t < 4; ++t) {
      aF[t] = *reinterpret_cast<const bf16x8*>(&As[wm * 64 + t * 16 + m16][quad * 8]);
      bF[t] = *reinterpret_cast<const bf16x8*>(&Ws[wn * 64 + t * 16 + m16][quad * 8]);
    }
#pragma unroll
    for (int mt = 0; mt < 4; ++mt)
#pragma unroll
      for (int nt = 0; nt < 4; ++nt)
        acc[mt][nt] = __builtin_amdgcn_mfma_f32_16x16x32_bf16(aF[mt], bF[nt], acc[mt][nt], 0, 0, 0);
    __syncthreads();
  }

  const int fl = (epi == 3) ? *flagp : 0;
  // C/D layout: col = lane&15, row = quad*4 + reg
#pragma unroll
  for (int mt = 0; mt < 4; ++mt) {
#pragma unroll
    for (int nt = 0; nt < 4; ++nt) {
      const int col = n0 + wn * 64 + nt * 16 + m16;
      const float bv = bf2f(bias[col]);
#pragma unroll
      for (int r = 0; r < 4; ++r) {
        const int row = m0 + wm * 64 + mt * 16 + quad * 4 + r;
        const size_t idx = (size_t)row * N + col;
        float v = acc[mt][nt][r] + bv;
        if (epi == 0) {
          outB[idx] = f2bf(v);
        } else if (epi == 1) {
          outB[idx] = f2bf(0.5f * v * (1.0f + erff(v * 0.70710678118654752f)));
        } else if (epi == 2) {
          residOut[idx] = residIn[idx] + v;
        } else {
          const float rr = residIn[idx] + v;
          if (fl) outF[idx] = rr; else outB[idx] = f2bf(rr);
        }
      }
    }
  }
}

// ---------------- RoPE in-place on qkv buffer [4096, 3072] ----------------
__global__ __launch_bounds__(256) void rope_kernel(bf16* __restrict__ qkv,
                                                   const bf16* __restrict__ cosb,
                                                   const bf16* __restrict__ sinb) {
  const int idx = blockIdx.x * 256 + threadIdx.x;  // over 4096*16*32
  const int i = idx & 31;
  const int h = (idx >> 5) & 15;
  const int r = idx >> 9;
  const int s = r & (Ssz - 1);
  const float c = bf2f(cosb[s * 32 + i]);
  const float sn = bf2f(sinb[s * 32 + i]);
  bf16* base = qkv + (size_t)r * (3 * Dm) + h * 64 + 2 * i;
  float x0 = bf2f(base[0]), x1 = bf2f(base[1]);
  base[0] = f2bf(x0 * c - x1 * sn);
  base[1] = f2bf(x0 * sn + x1 * c);
  x0 = bf2f(base[Dm]); x1 = bf2f(base[Dm + 1]);
  base[Dm] = f2bf(x0 * c - x1 * sn);
  base[Dm + 1] = f2bf(x0 * sn + x1 * c);
}

// ---------------- MFMA flash attention (round-3 verified) ----------------
__global__ __launch_bounds__(256) void attn_mfma(
    const bf16* __restrict__ Qb, const bf16* __restrict__ Kb, const bf16* __restrict__ Vb,
    bf16* __restrict__ Ob, int qStride, int kvStride, int kvLen, int causal, float scale) {
  __shared__ bf16 Ks[64][72];
  __shared__ bf16 Vt[64][72];
  __shared__ bf16 Ps[64][72];
  const int tid = threadIdx.x;
  const int wave = tid >> 6, lane = tid & 63;
  const int quad = lane >> 4, m16 = lane & 15;
  const int b = blockIdx.z, h = blockIdx.y;
  const int q0 = blockIdx.x * 64;
  const int sr = tid >> 2, sc = (tid & 3) * 16;

  {
    const bf16* qp = Qb + (size_t)(b * Ssz + q0 + sr) * qStride + h * 64 + sc;
    float4 a = reinterpret_cast<const float4*>(qp)[0];
    float4 bb2 = reinterpret_cast<const float4*>(qp)[1];
    *reinterpret_cast<float4*>(&Ps[sr][sc]) = a;
    *reinterpret_cast<float4*>(&Ps[sr][sc + 8]) = bb2;
  }
  __syncthreads();
  bf16x8 qf[2];
  qf[0] = *reinterpret_cast<const bf16x8*>(&Ps[wave * 16 + m16][quad * 8]);
  qf[1] = *reinterpret_cast<const bf16x8*>(&Ps[wave * 16 + m16][32 + quad * 8]);

  f32x4 oacc[4] = {};
  float mrow[4], lrow[4];
#pragma unroll
  for (int r = 0; r < 4; ++r) { mrow[r] = -30000.0f; lrow[r] = 0.0f; }

  const int nk = causal ? (q0 + 64) : kvLen;
  for (int kt = 0; kt < nk; kt += 64) {
    {
      const bf16* kp = Kb + (size_t)(b * kvLen + kt + sr) * kvStride + h * 64 + sc;
      float4 k1 = reinterpret_cast<const float4*>(kp)[0];
      float4 k2 = reinterpret_cast<const float4*>(kp)[1];
      *reinterpret_cast<float4*>(&Ks[sr][sc]) = k1;
      *reinterpret_cast<float4*>(&Ks[sr][sc + 8]) = k2;
      const bf16* vp = Vb + (size_t)(b * kvLen + kt + sr) * kvStride + h * 64 + sc;
      float4 v1 = reinterpret_cast<const float4*>(vp)[0];
      float4 v2 = reinterpret_cast<const float4*>(vp)[1];
      const bf16* tv1 = reinterpret_cast<const bf16*>(&v1);
      const bf16* tv2 = reinterpret_cast<const bf16*>(&v2);
#pragma unroll
      for (int j = 0; j < 8; ++j) {
        Vt[sc + j][sr] = tv1[j];
        Vt[sc + 8 + j][sr] = tv2[j];
      }
    }
    __syncthreads();

    f32x4 sacc[4] = {};
#pragma unroll
    for (int nt = 0; nt < 4; ++nt) {
      bf16x8 kf0 = *reinterpret_cast<const bf16x8*>(&Ks[nt * 16 + m16][quad * 8]);
      bf16x8 kf1 = *reinterpret_cast<const bf16x8*>(&Ks[nt * 16 + m16][32 + quad * 8]);
      sacc[nt] = __builtin_amdgcn_mfma_f32_16x16x32_bf16(qf[0], kf0, sacc[nt], 0, 0, 0);
      sacc[nt] = __builtin_amdgcn_mfma_f32_16x16x32_bf16(qf[1], kf1, sacc[nt], 0, 0, 0);
    }
    const bool dmask = (causal != 0) && (kt == q0);
#pragma unroll
    for (int nt = 0; nt < 4; ++nt) {
#pragma unroll
      for (int r = 0; r < 4; ++r) {
        float s = sacc[nt][r] * scale;
        if (dmask && (nt * 16 + m16 > wave * 16 + quad * 4 + r)) s = -30000.0f;
        sacc[nt][r] = s;
      }
    }

#pragma unroll
    for (int r = 0; r < 4; ++r) {
      float mx = fmaxf(fmaxf(sacc[0][r], sacc[1][r]), fmaxf(sacc[2][r], sacc[3][r]));
#pragma unroll
      for (int off = 1; off < 16; off <<= 1) mx = fmaxf(mx, __shfl_xor(mx, off));
      const float mn = fmaxf(mrow[r], mx);
      const float corr = __expf(mrow[r] - mn);
      mrow[r] = mn;
      float psum = 0.0f;
#pragma unroll
      for (int nt = 0; nt < 4; ++nt) {
        const float p = __expf(sacc[nt][r] - mn);
        sacc[nt][r] = p;
        psum += p;
      }
#pragma unroll
      for (int off = 1; off < 16; off <<= 1) psum += __shfl_xor(psum, off);
      lrow[r] = lrow[r] * corr + psum;
#pragma unroll
      for (int nt = 0; nt < 4; ++nt) oacc[nt][r] *= corr;
#pragma unroll
      for (int nt = 0; nt < 4; ++nt)
        Ps[wave * 16 + quad * 4 + r][nt * 16 + m16] = f2bf(sacc[nt][r]);
    }
    bf16x8 pf0 = *reinterpret_cast<const bf16x8*>(&Ps[wave * 16 + m16][quad * 8]);
    bf16x8 pf1 = *reinterpret_cast<const bf16x8*>(&Ps[wave * 16 + m16][32 + quad * 8]);
#pragma unroll
    for (int nt = 0; nt < 4; ++nt) {
      bf16x8 vf0 = *reinterpret_cast<const bf16x8*>(&Vt[nt * 16 + m16][quad * 8]);
      bf16x8 vf1 = *reinterpret_cast<const bf16x8*>(&Vt[nt * 16 + m16][32 + quad * 8]);
      oacc[nt] = __builtin_amdgcn_mfma_f32_16x16x32_bf16(pf0, vf0, oacc[nt], 0, 0, 0);
      oacc[nt] = __builtin_amdgcn_mfma_f32_16x16x32_bf16(pf1, vf1, oacc[nt], 0, 0, 0);
    }
    __syncthreads();
  }

  float inv[4];
#pragma unroll
  for (int r = 0; r < 4; ++r) inv[r] = 1.0f / lrow[r];
#pragma unroll
  for (int r = 0; r < 4; ++r) {
    bf16* op = Ob + (size_t)(b * Ssz + q0 + wave * 16 + quad * 4 + r) * Dm + h * 64 + m16;
#pragma unroll
    for (int nt = 0; nt < 4; ++nt) op[nt * 16] = f2bf(oacc[nt][r] * inv[r]);
  }
}

extern "C" void kernel_launch(void* const* d_in, const int* in_sizes, int n_in,
                              void* d_out, int out_size, void* d_ws, size_t ws_size,
                              hipStream_t stream) {
  char* ws = (char*)d_ws;
  int* flagp   = (int*)ws;                          // [0,1MB) control
  float* resid = (float*)(ws + (1ull << 20));       // 16MB fp32 residual
  bf16* xln    = (bf16*)(ws + (17ull << 20));       // 8MB LN output
  bf16* aout   = (bf16*)(ws + (25ull << 20));       // 8MB attn out
  bf16* big    = (bf16*)(ws + (33ull << 20));       // 32MB: qkv | qb | ffn1
  size_t off   = (65ull << 20);                     // canonical bf16 inputs

  detect_kernel<<<1, 64, 0, stream>>>((const unsigned*)d_in[3], flagp);

  CanonArgs ca;
  bf16* c[23];
  for (int i = 0; i < 23; ++i) {
    if (i == 2) { c[i] = nullptr; ca.src[i] = d_in[i]; ca.dst[i] = nullptr; ca.n[i] = 0; continue; }
    c[i] = (bf16*)(ws + off);
    const int n = in_sizes[i];
    off += ((size_t)n * 2 + 255) & ~(size_t)255;
    ca.src[i] = d_in[i];
    ca.dst[i] = c[i];
    ca.n[i] = n;
  }
  canon_all<<<dim3(256, 23), 256, 0, stream>>>(ca, resid, flagp);

  const bf16 *memory = c[1], *rope_cos = c[3], *rope_sin = c[4];
  const bf16 *qkv_w = c[5], *qkv_b = c[6], *out_w = c[7], *out_b = c[8];
  const bf16 *ca_in_w = c[9], *ca_in_b = c[10], *ca_out_w = c[11], *ca_out_b = c[12];
  const bf16 *ffn_w1 = c[13], *ffn_b1 = c[14], *ffn_w2 = c[15], *ffn_b2 = c[16];
  const bf16 *ln1_g = c[17], *ln1_b = c[18], *ln2_g = c[19], *ln2_b = c[20];
  const bf16 *ln3_g = c[21], *ln3_b = c[22];

  bf16* qb = big;
  bf16* kb = (bf16*)(ws + (41ull << 20));
  bf16* vb = (bf16*)(ws + (43ull << 20));
  bf16* outB = (bf16*)d_out;
  float* outF = (float*)d_out;

  const int ROWS = Bn * Ssz;   // 4096
  const float scale = 0.125f;  // 1/sqrt(64)

  // ---- self attention ----
  ln_kernel<<<ROWS, 256, 0, stream>>>(resid, ln1_g, ln1_b, xln);
  gemm128<<<dim3(ROWS / 128, (3 * Dm) / 128), 256, 0, stream>>>(
      xln, qkv_w, qkv_b, big, nullptr, nullptr, nullptr, nullptr, ROWS, 3 * Dm, Dm, 0);
  rope_kernel<<<(ROWS * Hh * (HDd / 2)) / 256, 256, 0, stream>>>(big, rope_cos, rope_sin);
  attn_mfma<<<dim3(Ssz / 64, Hh, Bn), 256, 0, stream>>>(
      big, big + Dm, big + 2 * Dm, aout, 3 * Dm, 3 * Dm, Ssz, 1, scale);
  gemm128<<<dim3(ROWS / 128, Dm / 128), 256, 0, stream>>>(
      aout, out_w, out_b, nullptr, nullptr, resid, resid, nullptr, ROWS, Dm, Dm, 2);

  // ---- cross attention ----
  ln_kernel<<<ROWS, 256, 0, stream>>>(resid, ln2_g, ln2_b, xln);
  gemm128<<<dim3(ROWS / 128, Dm / 128), 256, 0, stream>>>(
      xln, ca_in_w, ca_in_b, qb, nullptr, nullptr, nullptr, nullptr, ROWS, Dm, Dm, 0);
  gemm_bt<<<dim3((Bn * MEMn) / 64, Dm / 64), 256, 0, stream>>>(
      memory, ca_in_w + (size_t)Dm * Dm, ca_in_b + Dm, kb, nullptr, nullptr, nullptr, nullptr,
      Bn * MEMn, Dm, Dm, 0);
  gemm_bt<<<dim3((Bn * MEMn) / 64, Dm / 64), 256, 0, stream>>>(
      memory, ca_in_w + (size_t)2 * Dm * Dm, ca_in_b + 2 * Dm, vb, nullptr, nullptr, nullptr, nullptr,
      Bn * MEMn, Dm, Dm, 0);
  attn_mfma<<<dim3(Ssz / 64, Hh, Bn), 256, 0, stream>>>(
      qb, kb, vb, aout, Dm, Dm, MEMn, 0, scale);
  gemm128<<<dim3(ROWS / 128, Dm / 128), 256, 0, stream>>>(
      aout, ca_out_w, ca_out_b, nullptr, nullptr, resid, resid, nullptr, ROWS, Dm, Dm, 2);

  // ---- FFN ----
  ln_kernel<<<ROWS, 256, 0, stream>>>(resid, ln3_g, ln3_b, xln);
  gemm128<<<dim3(ROWS / 128, DFFn / 128), 256, 0, stream>>>(
      xln, ffn_w1, ffn_b1, big, nullptr, nullptr, nullptr, nullptr, ROWS, DFFn, Dm, 1);
  gemm128<<<dim3(ROWS / 128, Dm / 128), 256, 0, stream>>>(
      big, ffn_w2, ffn_b2, outB, outF, resid, nullptr, flagp, ROWS, Dm, DFFn, 3);
}

// Round 3
// 632.917 us; speedup vs baseline: 1.0380x; 1.0380x over previous
//
#include <hip/hip_runtime.h>
#include <hip/hip_bf16.h>

// PhraseDecoderLayer: B=4,S=1024,D=1024,H=16,HD=64,DFF=4096,MEM=256.
// Round 12: gemm128 -> counted-vmcnt DMA pipeline (T4). Evidence: round 9
// (reg depth-2 prefetch) and round 10 (no prefetch) hit IDENTICAL per-step
// time (~2200cy) => the shared __syncthreads vmcnt(0) drain is the wall
// (m131-m141; m218 counted-vs-drain = +38..73%). New K-loop: 3 rotating LDS
// buffers, stage t+2 while computing t, raw s_barrier + asm s_waitcnt
// vmcnt(4) (never 0 in-loop). One barrier per K-step. Stage target (t+2)%3
// is never the read buffer (t%3) => no read-vs-DMA race; reads of (t-1)%3
// completed before barrier t (their consuming MFMAs issued pre-barrier).
// Attention / kv GEMMs / LN / canon unchanged from passing rounds.

using bf16 = __hip_bfloat16;
typedef __bf16 bf16x8 __attribute__((ext_vector_type(8)));
typedef float f32x4 __attribute__((ext_vector_type(4)));

static constexpr int Bn = 4, Ssz = 1024, Dm = 1024, Hh = 16, HDd = 64, DFFn = 4096, MEMn = 256;

__device__ inline float bf2f(bf16 x) { return __bfloat162float(x); }
__device__ inline bf16 f2bf(float x) { return __float2bfloat16(x); }

// async global->LDS, 16B per lane. LDS dest must be linear in tid (wave-uniform
// base + lane*16); caller guarantees &lds byte offset == tid*16 within segment.
__device__ __forceinline__ void gload16(const bf16* g, bf16* l) {
  __builtin_amdgcn_global_load_lds(
      (const __attribute__((address_space(1))) void*)g,
      (__attribute__((address_space(3))) void*)l, 16, 0, 0);
}

// ---------------- dtype detect ----------------
__global__ void detect_kernel(const unsigned* __restrict__ cosw, int* __restrict__ flag) {
  if (threadIdx.x == 0) *flag = (cosw[0] == 0x3F800000u) ? 1 : 0;
}

// ---------------- fused canonicalize: all inputs -> bf16 (+f32 resid for seg0) ----
struct CanonArgs {
  const void* src[23];
  void* dst[23];
  int n[23];  // element count (0 = skip); all counts divisible by 4
};
__global__ __launch_bounds__(256) void canon_all(CanonArgs a, float* __restrict__ resid,
                                                 const int* __restrict__ flagp) {
  const int seg = blockIdx.y;
  const int n4 = a.n[seg] >> 2;
  if (n4 == 0) return;
  const int fl = *flagp;  // wave-uniform
  if (fl) {
    const float4* s = (const float4*)a.src[seg];
    bf16* d = (bf16*)a.dst[seg];
    for (int i = blockIdx.x * 256 + threadIdx.x; i < n4; i += gridDim.x * 256) {
      float4 v = s[i];
      bf16 t[4] = {f2bf(v.x), f2bf(v.y), f2bf(v.z), f2bf(v.w)};
      *reinterpret_cast<unsigned long long*>(d + i * 4) =
          *reinterpret_cast<unsigned long long*>(t);
      if (seg == 0) *reinterpret_cast<float4*>(resid + i * 4) = v;
    }
  } else {
    const unsigned long long* s = (const unsigned long long*)a.src[seg];
    unsigned long long* d = (unsigned long long*)a.dst[seg];
    for (int i = blockIdx.x * 256 + threadIdx.x; i < n4; i += gridDim.x * 256) {
      unsigned long long v = s[i];
      d[i] = v;
      if (seg == 0) {
        const unsigned short* u = reinterpret_cast<const unsigned short*>(&v);
        float4 f;
        f.x = __uint_as_float(((unsigned)u[0]) << 16);
        f.y = __uint_as_float(((unsigned)u[1]) << 16);
        f.z = __uint_as_float(((unsigned)u[2]) << 16);
        f.w = __uint_as_float(((unsigned)u[3]) << 16);
        *reinterpret_cast<float4*>(resid + i * 4) = f;
      }
    }
  }
}

// ---------------- LayerNorm (rows of 1024, fp32 in, bf16 out) ----------------
__global__ __launch_bounds__(256) void ln_kernel(const float* __restrict__ x,
                                                 const bf16* __restrict__ g,
                                                 const bf16* __restrict__ bb,
                                                 bf16* __restrict__ y) {
  const int row = blockIdx.x;
  const float* xr = x + (size_t)row * Dm;
  const int i0 = threadIdx.x * 4;
  float4 v = *reinterpret_cast<const float4*>(xr + i0);
  float s = v.x + v.y + v.z + v.w;
  float ss = v.x * v.x + v.y * v.y + v.z * v.z + v.w * v.w;
#pragma unroll
  for (int o = 32; o > 0; o >>= 1) {
    s += __shfl_down(s, o);
    ss += __shfl_down(ss, o);
  }
  __shared__ float shs[4], shss[4];
  const int wave = threadIdx.x >> 6, lane = threadIdx.x & 63;
  if (lane == 0) { shs[wave] = s; shss[wave] = ss; }
  __syncthreads();
  s = shs[0] + shs[1] + shs[2] + shs[3];
  ss = shss[0] + shss[1] + shss[2] + shss[3];
  const float mu = s * (1.0f / Dm);
  const float var = fmaxf(ss * (1.0f / Dm) - mu * mu, 0.0f);
  const float rs = rsqrtf(var + 1e-5f);
  bf16* yr = y + (size_t)row * Dm + i0;
  float vv[4] = {v.x, v.y, v.z, v.w};
#pragma unroll
  for (int j = 0; j < 4; ++j)
    yr[j] = f2bf((vv[j] - mu) * rs * bf2f(g[i0 + j]) + bf2f(bb[i0 + j]));
}

// ---------------- GEMM 64x64 (round-2 verified; used for M=1024 kv) --------
__global__ __launch_bounds__(256) void gemm_bt(
    const bf16* __restrict__ A, const bf16* __restrict__ W,
    const bf16* __restrict__ bias, bf16* __restrict__ outB, float* __restrict__ outF,
    const float* __restrict__ residIn, float* __restrict__ residOut,
    const int* __restrict__ flagp, int M, int N, int K, int epi) {
  __shared__ bf16 As[64][40];
  __shared__ bf16 Ws[64][40];
  const int tid = threadIdx.x;
  const int m0 = blockIdx.x * 64, n0 = blockIdx.y * 64;
  const int wave = tid >> 6, lane = tid & 63;
  const int wm = wave >> 1, wn = wave & 1;
  const int quad = lane >> 4, m16 = lane & 15;
  const int lr = tid >> 2, lc = (tid & 3) * 8;

  f32x4 acc[2][2] = {};

  const bf16* Ap = A + (size_t)(m0 + lr) * K + lc;
  const bf16* Wp = W + (size_t)(n0 + lr) * K + lc;
  for (int k0 = 0; k0 < K; k0 += 32) {
    float4 av = *reinterpret_cast<const float4*>(Ap + k0);
    float4 wv = *reinterpret_cast<const float4*>(Wp + k0);
    *reinterpret_cast<float4*>(&As[lr][lc]) = av;
    *reinterpret_cast<float4*>(&Ws[lr][lc]) = wv;
    __syncthreads();
    bf16x8 aF[2], bF[2];
#pragma unroll
    for (int t = 0; t < 2; ++t) {
      aF[t] = *reinterpret_cast<const bf16x8*>(&As[wm * 32 + t * 16 + m16][quad * 8]);
      bF[t] = *reinterpret_cast<const bf16x8*>(&Ws[wn * 32 + t * 16 + m16][quad * 8]);
    }
#pragma unroll
    for (int mt = 0; mt < 2; ++mt)
#pragma unroll
      for (int nt = 0; nt < 2; ++nt)
        acc[mt][nt] = __builtin_amdgcn_mfma_f32_16x16x32_bf16(aF[mt], bF[nt], acc[mt][nt], 0, 0, 0);
    __syncthreads();
  }
  const int fl = (epi == 3) ? *flagp : 0;
#pragma unroll
  for (int mt = 0; mt < 2; ++mt) {
#pragma unroll
    for (int nt = 0; nt < 2; ++nt) {
      const int col = n0 + wn * 32 + nt * 16 + m16;
      const float bv = bf2f(bias[col]);
#pragma unroll
      for (int r = 0; r < 4; ++r) {
        const int row = m0 + wm * 32 + mt * 16 + quad * 4 + r;
        const size_t idx = (size_t)row * N + col;
        float v = acc[mt][nt][r] + bv;
        if (epi == 0) {
          outB[idx] = f2bf(v);
        } else if (epi == 1) {
          outB[idx] = f2bf(0.5f * v * (1.0f + erff(v * 0.70710678118654752f)));
        } else if (epi == 2) {
          residOut[idx] = residIn[idx] + v;
        } else {
          const float rr = residIn[idx] + v;
          if (fl) outF[idx] = rr; else outB[idx] = f2bf(rr);
        }
      }
    }
  }
}

// ---------------- GEMM 128x128: counted-vmcnt DMA pipeline ----------------
// 3 rotating LDS buffers (48KB), depth-2 global_load_lds prefetch.
// Per K-step: s_waitcnt vmcnt(4) (stage t landed; t+1 still in flight) ->
// raw s_barrier -> STAGE(t+2 -> buf[(t+2)%3]) -> 8x ds_read_b128 -> 16 MFMA.
// vmcnt never drains to 0 in the main loop; loads ride across barriers.
__global__ __launch_bounds__(256) void gemm128(
    const bf16* __restrict__ A, const bf16* __restrict__ W,
    const bf16* __restrict__ bias, bf16* __restrict__ outB, float* __restrict__ outF,
    const float* __restrict__ residIn, float* __restrict__ residOut,
    const int* __restrict__ flagp, int M, int N, int K, int epi) {
  __shared__ bf16 As[3][128][32];
  __shared__ bf16 Ws[3][128][32];
  const int tid = threadIdx.x;
  const int wave = tid >> 6, lane = tid & 63;
  const int wm = wave >> 1, wn = wave & 1;
  const int quad = lane >> 4, m16 = lane & 15;
  const int m0 = blockIdx.x * 128, n0 = blockIdx.y * 128;

  const int sr = tid >> 2;       // 0..63 (tile row)
  const int sc = (tid & 3) * 8;  // 0,8,16,24 (k-col)
  const bf16* Ap = A + (size_t)(m0 + sr) * K + sc;
  const bf16* Wp = W + (size_t)(n0 + sr) * K + sc;
  const size_t rowOff = (size_t)64 * K;

  f32x4 acc[4][4] = {};

#define STAGE128(T, BUF)                                   \
  {                                                        \
    const int kk_ = (T) * 32;                              \
    gload16(Ap + kk_, &As[BUF][sr][sc]);                   \
    gload16(Ap + rowOff + kk_, &As[BUF][64 + sr][sc]);     \
    gload16(Wp + kk_, &Ws[BUF][sr][sc]);                   \
    gload16(Wp + rowOff + kk_, &Ws[BUF][64 + sr][sc]);     \
  }

  const int nsteps = K >> 5;  // >= 32 for all shapes here
  STAGE128(0, 0);
  STAGE128(1, 1);

  int rb = 0;  // read-buffer index = t % 3
  for (int t = 0; t < nsteps - 1; ++t) {
    asm volatile("s_waitcnt vmcnt(4)" ::: "memory");
    __builtin_amdgcn_s_barrier();
    __builtin_amdgcn_sched_barrier(0);
    if (t + 2 < nsteps) {
      int sb = rb + 2; if (sb >= 3) sb -= 3;
      STAGE128(t + 2, sb);
    }
    bf16x8 aF[4], bF[4];
#pragma unroll
    for (int tt = 0; tt < 4; ++tt) {
      aF[tt] = *reinterpret_cast<const bf16x8*>(&As[rb][wm * 64 + tt * 16 + m16][quad * 8]);
      bF[tt] = *reinterpret_cast<const bf16x8*>(&Ws[rb][wn * 64 + tt * 16 + m16][quad * 8]);
    }
#pragma unroll
    for (int mt = 0; mt < 4; ++mt)
#pragma unroll
      for (int nt = 0; nt < 4; ++nt)
        acc[mt][nt] = __builtin_amdgcn_mfma_f32_16x16x32_bf16(aF[mt], bF[nt], acc[mt][nt], 0, 0, 0);
    rb = (rb + 1 == 3) ? 0 : rb + 1;
  }
  // peeled last step: only stage nsteps-1 outstanding -> full drain
  {
    asm volatile("s_waitcnt vmcnt(0)" ::: "memory");
    __builtin_amdgcn_s_barrier();
    __builtin_amdgcn_sched_barrier(0);
    bf16x8 aF[4], bF[4];
#pragma unroll
    for (int tt = 0; tt < 4; ++tt) {
      aF[tt] = *reinterpret_cast<const bf16x8*>(&As[rb][wm * 64 + tt * 16 + m16][quad * 8]);
      bF[tt] = *reinterpret_cast<const bf16x8*>(&Ws[rb][wn * 64 + tt * 16 + m16][quad * 8]);
    }
#pragma unroll
    for (int mt = 0; mt < 4; ++mt)
#pragma unroll
      for (int nt = 0; nt < 4; ++nt)
        acc[mt][nt] = __builtin_amdgcn_mfma_f32_16x16x32_bf16(aF[mt], bF[nt], acc[mt][nt], 0, 0, 0);
  }
#undef STAGE128

  const int fl = (epi == 3) ? *flagp : 0;
  // C/D layout: col = lane&15, row = quad*4 + reg
#pragma unroll
  for (int mt = 0; mt < 4; ++mt) {
#pragma unroll
    for (int nt = 0; nt < 4; ++nt) {
      const int col = n0 + wn * 64 + nt * 16 + m16;
      const float bv = bf2f(bias[col]);
#pragma unroll
      for (int r = 0; r < 4; ++r) {
        const int row = m0 + wm * 64 + mt * 16 + quad * 4 + r;
        const size_t idx = (size_t)row * N + col;
        float v = acc[mt][nt][r] + bv;
        if (epi == 0) {
          outB[idx] = f2bf(v);
        } else if (epi == 1) {
          outB[idx] = f2bf(0.5f * v * (1.0f + erff(v * 0.70710678118654752f)));
        } else if (epi == 2) {
          residOut[idx] = residIn[idx] + v;
        } else {
          const float rr = residIn[idx] + v;
          if (fl) outF[idx] = rr; else outB[idx] = f2bf(rr);
        }
      }
    }
  }
}

// ---------------- RoPE in-place on qkv buffer [4096, 3072] ----------------
__global__ __launch_bounds__(256) void rope_kernel(bf16* __restrict__ qkv,
                                                   const bf16* __restrict__ cosb,
                                                   const bf16* __restrict__ sinb) {
  const int idx = blockIdx.x * 256 + threadIdx.x;  // over 4096*16*32
  const int i = idx & 31;
  const int h = (idx >> 5) & 15;
  const int r = idx >> 9;
  const int s = r & (Ssz - 1);
  const float c = bf2f(cosb[s * 32 + i]);
  const float sn = bf2f(sinb[s * 32 + i]);
  bf16* base = qkv + (size_t)r * (3 * Dm) + h * 64 + 2 * i;
  float x0 = bf2f(base[0]), x1 = bf2f(base[1]);
  base[0] = f2bf(x0 * c - x1 * sn);
  base[1] = f2bf(x0 * sn + x1 * c);
  x0 = bf2f(base[Dm]); x1 = bf2f(base[Dm + 1]);
  base[Dm] = f2bf(x0 * c - x1 * sn);
  base[Dm + 1] = f2bf(x0 * sn + x1 * c);
}

// ---------------- MFMA flash attention (round-3 verified) ----------------
__global__ __launch_bounds__(256) void attn_mfma(
    const bf16* __restrict__ Qb, const bf16* __restrict__ Kb, const bf16* __restrict__ Vb,
    bf16* __restrict__ Ob, int qStride, int kvStride, int kvLen, int causal, float scale) {
  __shared__ bf16 Ks[64][72];
  __shared__ bf16 Vt[64][72];
  __shared__ bf16 Ps[64][72];
  const int tid = threadIdx.x;
  const int wave = tid >> 6, lane = tid & 63;
  const int quad = lane >> 4, m16 = lane & 15;
  const int b = blockIdx.z, h = blockIdx.y;
  const int q0 = blockIdx.x * 64;
  const int sr = tid >> 2, sc = (tid & 3) * 16;

  {
    const bf16* qp = Qb + (size_t)(b * Ssz + q0 + sr) * qStride + h * 64 + sc;
    float4 a = reinterpret_cast<const float4*>(qp)[0];
    float4 bb2 = reinterpret_cast<const float4*>(qp)[1];
    *reinterpret_cast<float4*>(&Ps[sr][sc]) = a;
    *reinterpret_cast<float4*>(&Ps[sr][sc + 8]) = bb2;
  }
  __syncthreads();
  bf16x8 qf[2];
  qf[0] = *reinterpret_cast<const bf16x8*>(&Ps[wave * 16 + m16][quad * 8]);
  qf[1] = *reinterpret_cast<const bf16x8*>(&Ps[wave * 16 + m16][32 + quad * 8]);

  f32x4 oacc[4] = {};
  float mrow[4], lrow[4];
#pragma unroll
  for (int r = 0; r < 4; ++r) { mrow[r] = -30000.0f; lrow[r] = 0.0f; }

  const int nk = causal ? (q0 + 64) : kvLen;
  for (int kt = 0; kt < nk; kt += 64) {
    {
      const bf16* kp = Kb + (size_t)(b * kvLen + kt + sr) * kvStride + h * 64 + sc;
      float4 k1 = reinterpret_cast<const float4*>(kp)[0];
      float4 k2 = reinterpret_cast<const float4*>(kp)[1];
      *reinterpret_cast<float4*>(&Ks[sr][sc]) = k1;
      *reinterpret_cast<float4*>(&Ks[sr][sc + 8]) = k2;
      const bf16* vp = Vb + (size_t)(b * kvLen + kt + sr) * kvStride + h * 64 + sc;
      float4 v1 = reinterpret_cast<const float4*>(vp)[0];
      float4 v2 = reinterpret_cast<const float4*>(vp)[1];
      const bf16* tv1 = reinterpret_cast<const bf16*>(&v1);
      const bf16* tv2 = reinterpret_cast<const bf16*>(&v2);
#pragma unroll
      for (int j = 0; j < 8; ++j) {
        Vt[sc + j][sr] = tv1[j];
        Vt[sc + 8 + j][sr] = tv2[j];
      }
    }
    __syncthreads();

    f32x4 sacc[4] = {};
#pragma unroll
    for (int nt = 0; nt < 4; ++nt) {
      bf16x8 kf0 = *reinterpret_cast<const bf16x8*>(&Ks[nt * 16 + m16][quad * 8]);
      bf16x8 kf1 = *reinterpret_cast<const bf16x8*>(&Ks[nt * 16 + m16][32 + quad * 8]);
      sacc[nt] = __builtin_amdgcn_mfma_f32_16x16x32_bf16(qf[0], kf0, sacc[nt], 0, 0, 0);
      sacc[nt] = __builtin_amdgcn_mfma_f32_16x16x32_bf16(qf[1], kf1, sacc[nt], 0, 0, 0);
    }
    const bool dmask = (causal != 0) && (kt == q0);
#pragma unroll
    for (int nt = 0; nt < 4; ++nt) {
#pragma unroll
      for (int r = 0; r < 4; ++r) {
        float s = sacc[nt][r] * scale;
        if (dmask && (nt * 16 + m16 > wave * 16 + quad * 4 + r)) s = -30000.0f;
        sacc[nt][r] = s;
      }
    }

#pragma unroll
    for (int r = 0; r < 4; ++r) {
      float mx = fmaxf(fmaxf(sacc[0][r], sacc[1][r]), fmaxf(sacc[2][r], sacc[3][r]));
#pragma unroll
      for (int off = 1; off < 16; off <<= 1) mx = fmaxf(mx, __shfl_xor(mx, off));
      const float mn = fmaxf(mrow[r], mx);
      const float corr = __expf(mrow[r] - mn);
      mrow[r] = mn;
      float psum = 0.0f;
#pragma unroll
      for (int nt = 0; nt < 4; ++nt) {
        const float p = __expf(sacc[nt][r] - mn);
        sacc[nt][r] = p;
        psum += p;
      }
#pragma unroll
      for (int off = 1; off < 16; off <<= 1) psum += __shfl_xor(psum, off);
      lrow[r] = lrow[r] * corr + psum;
#pragma unroll
      for (int nt = 0; nt < 4; ++nt) oacc[nt][r] *= corr;
#pragma unroll
      for (int nt = 0; nt < 4; ++nt)
        Ps[wave * 16 + quad * 4 + r][nt * 16 + m16] = f2bf(sacc[nt][r]);
    }
    bf16x8 pf0 = *reinterpret_cast<const bf16x8*>(&Ps[wave * 16 + m16][quad * 8]);
    bf16x8 pf1 = *reinterpret_cast<const bf16x8*>(&Ps[wave * 16 + m16][32 + quad * 8]);
#pragma unroll
    for (int nt = 0; nt < 4; ++nt) {
      bf16x8 vf0 = *reinterpret_cast<const bf16x8*>(&Vt[nt * 16 + m16][quad * 8]);
      bf16x8 vf1 = *reinterpret_cast<const bf16x8*>(&Vt[nt * 16 + m16][32 + quad * 8]);
      oacc[nt] = __builtin_amdgcn_mfma_f32_16x16x32_bf16(pf0, vf0, oacc[nt], 0, 0, 0);
      oacc[nt] = __builtin_amdgcn_mfma_f32_16x16x32_bf16(pf1, vf1, oacc[nt], 0, 0, 0);
    }
    __syncthreads();
  }

  float inv[4];
#pragma unroll
  for (int r = 0; r < 4; ++r) inv[r] = 1.0f / lrow[r];
#pragma unroll
  for (int r = 0; r < 4; ++r) {
    bf16* op = Ob + (size_t)(b * Ssz + q0 + wave * 16 + quad * 4 + r) * Dm + h * 64 + m16;
#pragma unroll
    for (int nt = 0; nt < 4; ++nt) op[nt * 16] = f2bf(oacc[nt][r] * inv[r]);
  }
}

extern "C" void kernel_launch(void* const* d_in, const int* in_sizes, int n_in,
                              void* d_out, int out_size, void* d_ws, size_t ws_size,
                              hipStream_t stream) {
  char* ws = (char*)d_ws;
  int* flagp   = (int*)ws;                          // [0,1MB) control
  float* resid = (float*)(ws + (1ull << 20));       // 16MB fp32 residual
  bf16* xln    = (bf16*)(ws + (17ull << 20));       // 8MB LN output
  bf16* aout   = (bf16*)(ws + (25ull << 20));       // 8MB attn out
  bf16* big    = (bf16*)(ws + (33ull << 20));       // 32MB: qkv | qb | ffn1
  size_t off   = (65ull << 20);                     // canonical bf16 inputs

  detect_kernel<<<1, 64, 0, stream>>>((const unsigned*)d_in[3], flagp);

  CanonArgs ca;
  bf16* c[23];
  for (int i = 0; i < 23; ++i) {
    if (i == 2) { c[i] = nullptr; ca.src[i] = d_in[i]; ca.dst[i] = nullptr; ca.n[i] = 0; continue; }
    c[i] = (bf16*)(ws + off);
    const int n = in_sizes[i];
    off += ((size_t)n * 2 + 255) & ~(size_t)255;
    ca.src[i] = d_in[i];
    ca.dst[i] = c[i];
    ca.n[i] = n;
  }
  canon_all<<<dim3(256, 23), 256, 0, stream>>>(ca, resid, flagp);

  const bf16 *memory = c[1], *rope_cos = c[3], *rope_sin = c[4];
  const bf16 *qkv_w = c[5], *qkv_b = c[6], *out_w = c[7], *out_b = c[8];
  const bf16 *ca_in_w = c[9], *ca_in_b = c[10], *ca_out_w = c[11], *ca_out_b = c[12];
  const bf16 *ffn_w1 = c[13], *ffn_b1 = c[14], *ffn_w2 = c[15], *ffn_b2 = c[16];
  const bf16 *ln1_g = c[17], *ln1_b = c[18], *ln2_g = c[19], *ln2_b = c[20];
  const bf16 *ln3_g = c[21], *ln3_b = c[22];

  bf16* qb = big;
  bf16* kb = (bf16*)(ws + (41ull << 20));
  bf16* vb = (bf16*)(ws + (43ull << 20));
  bf16* outB = (bf16*)d_out;
  float* outF = (float*)d_out;

  const int ROWS = Bn * Ssz;   // 4096
  const float scale = 0.125f;  // 1/sqrt(64)

  // ---- self attention ----
  ln_kernel<<<ROWS, 256, 0, stream>>>(resid, ln1_g, ln1_b, xln);
  gemm128<<<dim3(ROWS / 128, (3 * Dm) / 128), 256, 0, stream>>>(
      xln, qkv_w, qkv_b, big, nullptr, nullptr, nullptr, nullptr, ROWS, 3 * Dm, Dm, 0);
  rope_kernel<<<(ROWS * Hh * (HDd / 2)) / 256, 256, 0, stream>>>(big, rope_cos, rope_sin);
  attn_mfma<<<dim3(Ssz / 64, Hh, Bn), 256, 0, stream>>>(
      big, big + Dm, big + 2 * Dm, aout, 3 * Dm, 3 * Dm, Ssz, 1, scale);
  gemm128<<<dim3(ROWS / 128, Dm / 128), 256, 0, stream>>>(
      aout, out_w, out_b, nullptr, nullptr, resid, resid, nullptr, ROWS, Dm, Dm, 2);

  // ---- cross attention ----
  ln_kernel<<<ROWS, 256, 0, stream>>>(resid, ln2_g, ln2_b, xln);
  gemm128<<<dim3(ROWS / 128, Dm / 128), 256, 0, stream>>>(
      xln, ca_in_w, ca_in_b, qb, nullptr, nullptr, nullptr, nullptr, ROWS, Dm, Dm, 0);
  gemm_bt<<<dim3((Bn * MEMn) / 64, Dm / 64), 256, 0, stream>>>(
      memory, ca_in_w + (size_t)Dm * Dm, ca_in_b + Dm, kb, nullptr, nullptr, nullptr, nullptr,
      Bn * MEMn, Dm, Dm, 0);
  gemm_bt<<<dim3((Bn * MEMn) / 64, Dm / 64), 256, 0, stream>>>(
      memory, ca_in_w + (size_t)2 * Dm * Dm, ca_in_b + 2 * Dm, vb, nullptr, nullptr, nullptr, nullptr,
      Bn * MEMn, Dm, Dm, 0);
  attn_mfma<<<dim3(Ssz / 64, Hh, Bn), 256, 0, stream>>>(
      qb, kb, vb, aout, Dm, Dm, MEMn, 0, scale);
  gemm128<<<dim3(ROWS / 128, Dm / 128), 256, 0, stream>>>(
      aout, ca_out_w, ca_out_b, nullptr, nullptr, resid, resid, nullptr, ROWS, Dm, Dm, 2);

  // ---- FFN ----
  ln_kernel<<<ROWS, 256, 0, stream>>>(resid, ln3_g, ln3_b, xln);
  gemm128<<<dim3(ROWS / 128, DFFn / 128), 256, 0, stream>>>(
      xln, ffn_w1, ffn_b1, big, nullptr, nullptr, nullptr, nullptr, ROWS, DFFn, Dm, 1);
  gemm128<<<dim3(ROWS / 128, Dm / 128), 256, 0, stream>>>(
      big, ffn_w2, ffn_b2, outB, outF, resid, nullptr, flagp, ROWS, Dm, DFFn, 3);
}

// Round 4
// 589.413 us; speedup vs baseline: 1.1146x; 1.0738x over previous
//
#include <hip/hip_runtime.h>
#include <hip/hip_bf16.h>

// PhraseDecoderLayer: B=4,S=1024,D=1024,H=16,HD=64,DFF=4096,MEM=256.
// Round 13: gemm128 depth-4 DMA pipeline. Round-12 post-mortem: per-step
// 1963cy ~= full HBM latency + compute despite vmcnt(4) => each step exposed
// the latency of its OWN stage (likely compiler-inserted conservative vmcnt
// before ds_read due to LDS-DMA aliasing; stage was issued BEFORE reads).
// Changes: (a) 5 rotating buffers, stage t+4 (depth-4: 4S >= Lat => S ~=
// max(compute 271cy, Lat/4 ~400cy)); (b) ds_reads FIRST after barrier, STAGE
// after reads (conservative drain now covers >=1-step-old loads => worst
// case (Lat+C)/2, not Lat+C); (c) graduated tail waits vmcnt(8/4/0) on 3
// peeled steps. One s_barrier per K-step (writer of buf b at step t+1 is
// after barrier t+1; readers of b at step t finish pre-barrier t+1).
// Attention / kv GEMMs / LN / canon unchanged from passing rounds.

using bf16 = __hip_bfloat16;
typedef __bf16 bf16x8 __attribute__((ext_vector_type(8)));
typedef float f32x4 __attribute__((ext_vector_type(4)));

static constexpr int Bn = 4, Ssz = 1024, Dm = 1024, Hh = 16, HDd = 64, DFFn = 4096, MEMn = 256;

__device__ inline float bf2f(bf16 x) { return __bfloat162float(x); }
__device__ inline bf16 f2bf(float x) { return __float2bfloat16(x); }

// async global->LDS, 16B per lane. LDS dest must be linear in tid (wave-uniform
// base + lane*16); caller guarantees &lds byte offset == tid*16 within segment.
__device__ __forceinline__ void gload16(const bf16* g, bf16* l) {
  __builtin_amdgcn_global_load_lds(
      (const __attribute__((address_space(1))) void*)g,
      (__attribute__((address_space(3))) void*)l, 16, 0, 0);
}

// ---------------- dtype detect ----------------
__global__ void detect_kernel(const unsigned* __restrict__ cosw, int* __restrict__ flag) {
  if (threadIdx.x == 0) *flag = (cosw[0] == 0x3F800000u) ? 1 : 0;
}

// ---------------- fused canonicalize: all inputs -> bf16 (+f32 resid for seg0) ----
struct CanonArgs {
  const void* src[23];
  void* dst[23];
  int n[23];  // element count (0 = skip); all counts divisible by 4
};
__global__ __launch_bounds__(256) void canon_all(CanonArgs a, float* __restrict__ resid,
                                                 const int* __restrict__ flagp) {
  const int seg = blockIdx.y;
  const int n4 = a.n[seg] >> 2;
  if (n4 == 0) return;
  const int fl = *flagp;  // wave-uniform
  if (fl) {
    const float4* s = (const float4*)a.src[seg];
    bf16* d = (bf16*)a.dst[seg];
    for (int i = blockIdx.x * 256 + threadIdx.x; i < n4; i += gridDim.x * 256) {
      float4 v = s[i];
      bf16 t[4] = {f2bf(v.x), f2bf(v.y), f2bf(v.z), f2bf(v.w)};
      *reinterpret_cast<unsigned long long*>(d + i * 4) =
          *reinterpret_cast<unsigned long long*>(t);
      if (seg == 0) *reinterpret_cast<float4*>(resid + i * 4) = v;
    }
  } else {
    const unsigned long long* s = (const unsigned long long*)a.src[seg];
    unsigned long long* d = (unsigned long long*)a.dst[seg];
    for (int i = blockIdx.x * 256 + threadIdx.x; i < n4; i += gridDim.x * 256) {
      unsigned long long v = s[i];
      d[i] = v;
      if (seg == 0) {
        const unsigned short* u = reinterpret_cast<const unsigned short*>(&v);
        float4 f;
        f.x = __uint_as_float(((unsigned)u[0]) << 16);
        f.y = __uint_as_float(((unsigned)u[1]) << 16);
        f.z = __uint_as_float(((unsigned)u[2]) << 16);
        f.w = __uint_as_float(((unsigned)u[3]) << 16);
        *reinterpret_cast<float4*>(resid + i * 4) = f;
      }
    }
  }
}

// ---------------- LayerNorm (rows of 1024, fp32 in, bf16 out) ----------------
__global__ __launch_bounds__(256) void ln_kernel(const float* __restrict__ x,
                                                 const bf16* __restrict__ g,
                                                 const bf16* __restrict__ bb,
                                                 bf16* __restrict__ y) {
  const int row = blockIdx.x;
  const float* xr = x + (size_t)row * Dm;
  const int i0 = threadIdx.x * 4;
  float4 v = *reinterpret_cast<const float4*>(xr + i0);
  float s = v.x + v.y + v.z + v.w;
  float ss = v.x * v.x + v.y * v.y + v.z * v.z + v.w * v.w;
#pragma unroll
  for (int o = 32; o > 0; o >>= 1) {
    s += __shfl_down(s, o);
    ss += __shfl_down(ss, o);
  }
  __shared__ float shs[4], shss[4];
  const int wave = threadIdx.x >> 6, lane = threadIdx.x & 63;
  if (lane == 0) { shs[wave] = s; shss[wave] = ss; }
  __syncthreads();
  s = shs[0] + shs[1] + shs[2] + shs[3];
  ss = shss[0] + shss[1] + shss[2] + shss[3];
  const float mu = s * (1.0f / Dm);
  const float var = fmaxf(ss * (1.0f / Dm) - mu * mu, 0.0f);
  const float rs = rsqrtf(var + 1e-5f);
  bf16* yr = y + (size_t)row * Dm + i0;
  float vv[4] = {v.x, v.y, v.z, v.w};
#pragma unroll
  for (int j = 0; j < 4; ++j)
    yr[j] = f2bf((vv[j] - mu) * rs * bf2f(g[i0 + j]) + bf2f(bb[i0 + j]));
}

// ---------------- GEMM 64x64 (round-2 verified; used for M=1024 kv) --------
__global__ __launch_bounds__(256) void gemm_bt(
    const bf16* __restrict__ A, const bf16* __restrict__ W,
    const bf16* __restrict__ bias, bf16* __restrict__ outB, float* __restrict__ outF,
    const float* __restrict__ residIn, float* __restrict__ residOut,
    const int* __restrict__ flagp, int M, int N, int K, int epi) {
  __shared__ bf16 As[64][40];
  __shared__ bf16 Ws[64][40];
  const int tid = threadIdx.x;
  const int m0 = blockIdx.x * 64, n0 = blockIdx.y * 64;
  const int wave = tid >> 6, lane = tid & 63;
  const int wm = wave >> 1, wn = wave & 1;
  const int quad = lane >> 4, m16 = lane & 15;
  const int lr = tid >> 2, lc = (tid & 3) * 8;

  f32x4 acc[2][2] = {};

  const bf16* Ap = A + (size_t)(m0 + lr) * K + lc;
  const bf16* Wp = W + (size_t)(n0 + lr) * K + lc;
  for (int k0 = 0; k0 < K; k0 += 32) {
    float4 av = *reinterpret_cast<const float4*>(Ap + k0);
    float4 wv = *reinterpret_cast<const float4*>(Wp + k0);
    *reinterpret_cast<float4*>(&As[lr][lc]) = av;
    *reinterpret_cast<float4*>(&Ws[lr][lc]) = wv;
    __syncthreads();
    bf16x8 aF[2], bF[2];
#pragma unroll
    for (int t = 0; t < 2; ++t) {
      aF[t] = *reinterpret_cast<const bf16x8*>(&As[wm * 32 + t * 16 + m16][quad * 8]);
      bF[t] = *reinterpret_cast<const bf16x8*>(&Ws[wn * 32 + t * 16 + m16][quad * 8]);
    }
#pragma unroll
    for (int mt = 0; mt < 2; ++mt)
#pragma unroll
      for (int nt = 0; nt < 2; ++nt)
        acc[mt][nt] = __builtin_amdgcn_mfma_f32_16x16x32_bf16(aF[mt], bF[nt], acc[mt][nt], 0, 0, 0);
    __syncthreads();
  }
  const int fl = (epi == 3) ? *flagp : 0;
#pragma unroll
  for (int mt = 0; mt < 2; ++mt) {
#pragma unroll
    for (int nt = 0; nt < 2; ++nt) {
      const int col = n0 + wn * 32 + nt * 16 + m16;
      const float bv = bf2f(bias[col]);
#pragma unroll
      for (int r = 0; r < 4; ++r) {
        const int row = m0 + wm * 32 + mt * 16 + quad * 4 + r;
        const size_t idx = (size_t)row * N + col;
        float v = acc[mt][nt][r] + bv;
        if (epi == 0) {
          outB[idx] = f2bf(v);
        } else if (epi == 1) {
          outB[idx] = f2bf(0.5f * v * (1.0f + erff(v * 0.70710678118654752f)));
        } else if (epi == 2) {
          residOut[idx] = residIn[idx] + v;
        } else {
          const float rr = residIn[idx] + v;
          if (fl) outF[idx] = rr; else outB[idx] = f2bf(rr);
        }
      }
    }
  }
}

// ---------------- GEMM 128x128: depth-4 counted-vmcnt DMA pipeline ---------
// 5 rotating LDS buffers (80KB). Per K-step t:
//   s_waitcnt vmcnt(12)  (tile t landed; t+1..t+3 in flight)
//   s_barrier            (all waves' tile-t DMA visible)
//   8x ds_read_b128 (buf t%5)  [reads first]
//   STAGE tile t+4 -> buf (t+4)%5
//   16 MFMA
// Tail: 3 peeled steps with vmcnt(8)/(4)/(0).
__global__ __launch_bounds__(256) void gemm128(
    const bf16* __restrict__ A, const bf16* __restrict__ W,
    const bf16* __restrict__ bias, bf16* __restrict__ outB, float* __restrict__ outF,
    const float* __restrict__ residIn, float* __restrict__ residOut,
    const int* __restrict__ flagp, int M, int N, int K, int epi) {
  __shared__ bf16 As[5][128][32];
  __shared__ bf16 Ws[5][128][32];
  const int tid = threadIdx.x;
  const int wave = tid >> 6, lane = tid & 63;
  const int wm = wave >> 1, wn = wave & 1;
  const int quad = lane >> 4, m16 = lane & 15;
  const int m0 = blockIdx.x * 128, n0 = blockIdx.y * 128;

  const int sr = tid >> 2;       // 0..63 (tile row)
  const int sc = (tid & 3) * 8;  // 0,8,16,24 (k-col)
  const bf16* Ap = A + (size_t)(m0 + sr) * K + sc;
  const bf16* Wp = W + (size_t)(n0 + sr) * K + sc;
  const size_t rowOff = (size_t)64 * K;

  f32x4 acc[4][4] = {};

#define STAGE128(T, BUF)                                   \
  {                                                        \
    const int kk_ = (T) * 32;                              \
    gload16(Ap + kk_, &As[BUF][sr][sc]);                   \
    gload16(Ap + rowOff + kk_, &As[BUF][64 + sr][sc]);     \
    gload16(Wp + kk_, &Ws[BUF][sr][sc]);                   \
    gload16(Wp + rowOff + kk_, &Ws[BUF][64 + sr][sc]);     \
  }

#define READS128(RB)                                                                      \
  _Pragma("unroll") for (int tt = 0; tt < 4; ++tt) {                                      \
    aF[tt] = *reinterpret_cast<const bf16x8*>(&As[RB][wm * 64 + tt * 16 + m16][quad * 8]); \
    bF[tt] = *reinterpret_cast<const bf16x8*>(&Ws[RB][wn * 64 + tt * 16 + m16][quad * 8]); \
  }

#define MFMAS128                                                                          \
  _Pragma("unroll") for (int mt = 0; mt < 4; ++mt)                                        \
  _Pragma("unroll") for (int nt = 0; nt < 4; ++nt)                                        \
    acc[mt][nt] = __builtin_amdgcn_mfma_f32_16x16x32_bf16(aF[mt], bF[nt], acc[mt][nt], 0, 0, 0);

  const int nsteps = K >> 5;  // K >= 128 for all shapes here (K=1024 or 4096)
  STAGE128(0, 0)
  STAGE128(1, 1)
  STAGE128(2, 2)
  STAGE128(3, 3)

  int rb = 0, sb = 4;
  for (int t = 0; t < nsteps - 3; ++t) {
    asm volatile("s_waitcnt vmcnt(12)" ::: "memory");
    __builtin_amdgcn_s_barrier();
    __builtin_amdgcn_sched_barrier(0);
    bf16x8 aF[4], bF[4];
    READS128(rb)
    __builtin_amdgcn_sched_barrier(0);
    if (t + 4 < nsteps) { STAGE128(t + 4, sb) }
    __builtin_amdgcn_sched_barrier(0);
    MFMAS128
    rb = (rb + 1 == 5) ? 0 : rb + 1;
    sb = (sb + 1 == 5) ? 0 : sb + 1;
  }
  {  // t = nsteps-3: tiles t..nsteps-1 outstanding (12) -> wait 8 = tile t
    asm volatile("s_waitcnt vmcnt(8)" ::: "memory");
    __builtin_amdgcn_s_barrier();
    __builtin_amdgcn_sched_barrier(0);
    bf16x8 aF[4], bF[4];
    READS128(rb)
    MFMAS128
    rb = (rb + 1 == 5) ? 0 : rb + 1;
  }
  {  // t = nsteps-2
    asm volatile("s_waitcnt vmcnt(4)" ::: "memory");
    __builtin_amdgcn_s_barrier();
    __builtin_amdgcn_sched_barrier(0);
    bf16x8 aF[4], bF[4];
    READS128(rb)
    MFMAS128
    rb = (rb + 1 == 5) ? 0 : rb + 1;
  }
  {  // t = nsteps-1
    asm volatile("s_waitcnt vmcnt(0)" ::: "memory");
    __builtin_amdgcn_s_barrier();
    __builtin_amdgcn_sched_barrier(0);
    bf16x8 aF[4], bF[4];
    READS128(rb)
    MFMAS128
  }
#undef STAGE128
#undef READS128
#undef MFMAS128

  const int fl = (epi == 3) ? *flagp : 0;
  // C/D layout: col = lane&15, row = quad*4 + reg
#pragma unroll
  for (int mt = 0; mt < 4; ++mt) {
#pragma unroll
    for (int nt = 0; nt < 4; ++nt) {
      const int col = n0 + wn * 64 + nt * 16 + m16;
      const float bv = bf2f(bias[col]);
#pragma unroll
      for (int r = 0; r < 4; ++r) {
        const int row = m0 + wm * 64 + mt * 16 + quad * 4 + r;
        const size_t idx = (size_t)row * N + col;
        float v = acc[mt][nt][r] + bv;
        if (epi == 0) {
          outB[idx] = f2bf(v);
        } else if (epi == 1) {
          outB[idx] = f2bf(0.5f * v * (1.0f + erff(v * 0.70710678118654752f)));
        } else if (epi == 2) {
          residOut[idx] = residIn[idx] + v;
        } else {
          const float rr = residIn[idx] + v;
          if (fl) outF[idx] = rr; else outB[idx] = f2bf(rr);
        }
      }
    }
  }
}

// ---------------- RoPE in-place on qkv buffer [4096, 3072] ----------------
__global__ __launch_bounds__(256) void rope_kernel(bf16* __restrict__ qkv,
                                                   const bf16* __restrict__ cosb,
                                                   const bf16* __restrict__ sinb) {
  const int idx = blockIdx.x * 256 + threadIdx.x;  // over 4096*16*32
  const int i = idx & 31;
  const int h = (idx >> 5) & 15;
  const int r = idx >> 9;
  const int s = r & (Ssz - 1);
  const float c = bf2f(cosb[s * 32 + i]);
  const float sn = bf2f(sinb[s * 32 + i]);
  bf16* base = qkv + (size_t)r * (3 * Dm) + h * 64 + 2 * i;
  float x0 = bf2f(base[0]), x1 = bf2f(base[1]);
  base[0] = f2bf(x0 * c - x1 * sn);
  base[1] = f2bf(x0 * sn + x1 * c);
  x0 = bf2f(base[Dm]); x1 = bf2f(base[Dm + 1]);
  base[Dm] = f2bf(x0 * c - x1 * sn);
  base[Dm + 1] = f2bf(x0 * sn + x1 * c);
}

// ---------------- MFMA flash attention (round-3 verified) ----------------
__global__ __launch_bounds__(256) void attn_mfma(
    const bf16* __restrict__ Qb, const bf16* __restrict__ Kb, const bf16* __restrict__ Vb,
    bf16* __restrict__ Ob, int qStride, int kvStride, int kvLen, int causal, float scale) {
  __shared__ bf16 Ks[64][72];
  __shared__ bf16 Vt[64][72];
  __shared__ bf16 Ps[64][72];
  const int tid = threadIdx.x;
  const int wave = tid >> 6, lane = tid & 63;
  const int quad = lane >> 4, m16 = lane & 15;
  const int b = blockIdx.z, h = blockIdx.y;
  const int q0 = blockIdx.x * 64;
  const int sr = tid >> 2, sc = (tid & 3) * 16;

  {
    const bf16* qp = Qb + (size_t)(b * Ssz + q0 + sr) * qStride + h * 64 + sc;
    float4 a = reinterpret_cast<const float4*>(qp)[0];
    float4 bb2 = reinterpret_cast<const float4*>(qp)[1];
    *reinterpret_cast<float4*>(&Ps[sr][sc]) = a;
    *reinterpret_cast<float4*>(&Ps[sr][sc + 8]) = bb2;
  }
  __syncthreads();
  bf16x8 qf[2];
  qf[0] = *reinterpret_cast<const bf16x8*>(&Ps[wave * 16 + m16][quad * 8]);
  qf[1] = *reinterpret_cast<const bf16x8*>(&Ps[wave * 16 + m16][32 + quad * 8]);

  f32x4 oacc[4] = {};
  float mrow[4], lrow[4];
#pragma unroll
  for (int r = 0; r < 4; ++r) { mrow[r] = -30000.0f; lrow[r] = 0.0f; }

  const int nk = causal ? (q0 + 64) : kvLen;
  for (int kt = 0; kt < nk; kt += 64) {
    {
      const bf16* kp = Kb + (size_t)(b * kvLen + kt + sr) * kvStride + h * 64 + sc;
      float4 k1 = reinterpret_cast<const float4*>(kp)[0];
      float4 k2 = reinterpret_cast<const float4*>(kp)[1];
      *reinterpret_cast<float4*>(&Ks[sr][sc]) = k1;
      *reinterpret_cast<float4*>(&Ks[sr][sc + 8]) = k2;
      const bf16* vp = Vb + (size_t)(b * kvLen + kt + sr) * kvStride + h * 64 + sc;
      float4 v1 = reinterpret_cast<const float4*>(vp)[0];
      float4 v2 = reinterpret_cast<const float4*>(vp)[1];
      const bf16* tv1 = reinterpret_cast<const bf16*>(&v1);
      const bf16* tv2 = reinterpret_cast<const bf16*>(&v2);
#pragma unroll
      for (int j = 0; j < 8; ++j) {
        Vt[sc + j][sr] = tv1[j];
        Vt[sc + 8 + j][sr] = tv2[j];
      }
    }
    __syncthreads();

    f32x4 sacc[4] = {};
#pragma unroll
    for (int nt = 0; nt < 4; ++nt) {
      bf16x8 kf0 = *reinterpret_cast<const bf16x8*>(&Ks[nt * 16 + m16][quad * 8]);
      bf16x8 kf1 = *reinterpret_cast<const bf16x8*>(&Ks[nt * 16 + m16][32 + quad * 8]);
      sacc[nt] = __builtin_amdgcn_mfma_f32_16x16x32_bf16(qf[0], kf0, sacc[nt], 0, 0, 0);
      sacc[nt] = __builtin_amdgcn_mfma_f32_16x16x32_bf16(qf[1], kf1, sacc[nt], 0, 0, 0);
    }
    const bool dmask = (causal != 0) && (kt == q0);
#pragma unroll
    for (int nt = 0; nt < 4; ++nt) {
#pragma unroll
      for (int r = 0; r < 4; ++r) {
        float s = sacc[nt][r] * scale;
        if (dmask && (nt * 16 + m16 > wave * 16 + quad * 4 + r)) s = -30000.0f;
        sacc[nt][r] = s;
      }
    }

#pragma unroll
    for (int r = 0; r < 4; ++r) {
      float mx = fmaxf(fmaxf(sacc[0][r], sacc[1][r]), fmaxf(sacc[2][r], sacc[3][r]));
#pragma unroll
      for (int off = 1; off < 16; off <<= 1) mx = fmaxf(mx, __shfl_xor(mx, off));
      const float mn = fmaxf(mrow[r], mx);
      const float corr = __expf(mrow[r] - mn);
      mrow[r] = mn;
      float psum = 0.0f;
#pragma unroll
      for (int nt = 0; nt < 4; ++nt) {
        const float p = __expf(sacc[nt][r] - mn);
        sacc[nt][r] = p;
        psum += p;
      }
#pragma unroll
      for (int off = 1; off < 16; off <<= 1) psum += __shfl_xor(psum, off);
      lrow[r] = lrow[r] * corr + psum;
#pragma unroll
      for (int nt = 0; nt < 4; ++nt) oacc[nt][r] *= corr;
#pragma unroll
      for (int nt = 0; nt < 4; ++nt)
        Ps[wave * 16 + quad * 4 + r][nt * 16 + m16] = f2bf(sacc[nt][r]);
    }
    bf16x8 pf0 = *reinterpret_cast<const bf16x8*>(&Ps[wave * 16 + m16][quad * 8]);
    bf16x8 pf1 = *reinterpret_cast<const bf16x8*>(&Ps[wave * 16 + m16][32 + quad * 8]);
#pragma unroll
    for (int nt = 0; nt < 4; ++nt) {
      bf16x8 vf0 = *reinterpret_cast<const bf16x8*>(&Vt[nt * 16 + m16][quad * 8]);
      bf16x8 vf1 = *reinterpret_cast<const bf16x8*>(&Vt[nt * 16 + m16][32 + quad * 8]);
      oacc[nt] = __builtin_amdgcn_mfma_f32_16x16x32_bf16(pf0, vf0, oacc[nt], 0, 0, 0);
      oacc[nt] = __builtin_amdgcn_mfma_f32_16x16x32_bf16(pf1, vf1, oacc[nt], 0, 0, 0);
    }
    __syncthreads();
  }

  float inv[4];
#pragma unroll
  for (int r = 0; r < 4; ++r) inv[r] = 1.0f / lrow[r];
#pragma unroll
  for (int r = 0; r < 4; ++r) {
    bf16* op = Ob + (size_t)(b * Ssz + q0 + wave * 16 + quad * 4 + r) * Dm + h * 64 + m16;
#pragma unroll
    for (int nt = 0; nt < 4; ++nt) op[nt * 16] = f2bf(oacc[nt][r] * inv[r]);
  }
}

extern "C" void kernel_launch(void* const* d_in, const int* in_sizes, int n_in,
                              void* d_out, int out_size, void* d_ws, size_t ws_size,
                              hipStream_t stream) {
  char* ws = (char*)d_ws;
  int* flagp   = (int*)ws;                          // [0,1MB) control
  float* resid = (float*)(ws + (1ull << 20));       // 16MB fp32 residual
  bf16* xln    = (bf16*)(ws + (17ull << 20));       // 8MB LN output
  bf16* aout   = (bf16*)(ws + (25ull << 20));       // 8MB attn out
  bf16* big    = (bf16*)(ws + (33ull << 20));       // 32MB: qkv | qb | ffn1
  size_t off   = (65ull << 20);                     // canonical bf16 inputs

  detect_kernel<<<1, 64, 0, stream>>>((const unsigned*)d_in[3], flagp);

  CanonArgs ca;
  bf16* c[23];
  for (int i = 0; i < 23; ++i) {
    if (i == 2) { c[i] = nullptr; ca.src[i] = d_in[i]; ca.dst[i] = nullptr; ca.n[i] = 0; continue; }
    c[i] = (bf16*)(ws + off);
    const int n = in_sizes[i];
    off += ((size_t)n * 2 + 255) & ~(size_t)255;
    ca.src[i] = d_in[i];
    ca.dst[i] = c[i];
    ca.n[i] = n;
  }
  canon_all<<<dim3(256, 23), 256, 0, stream>>>(ca, resid, flagp);

  const bf16 *memory = c[1], *rope_cos = c[3], *rope_sin = c[4];
  const bf16 *qkv_w = c[5], *qkv_b = c[6], *out_w = c[7], *out_b = c[8];
  const bf16 *ca_in_w = c[9], *ca_in_b = c[10], *ca_out_w = c[11], *ca_out_b = c[12];
  const bf16 *ffn_w1 = c[13], *ffn_b1 = c[14], *ffn_w2 = c[15], *ffn_b2 = c[16];
  const bf16 *ln1_g = c[17], *ln1_b = c[18], *ln2_g = c[19], *ln2_b = c[20];
  const bf16 *ln3_g = c[21], *ln3_b = c[22];

  bf16* qb = big;
  bf16* kb = (bf16*)(ws + (41ull << 20));
  bf16* vb = (bf16*)(ws + (43ull << 20));
  bf16* outB = (bf16*)d_out;
  float* outF = (float*)d_out;

  const int ROWS = Bn * Ssz;   // 4096
  const float scale = 0.125f;  // 1/sqrt(64)

  // ---- self attention ----
  ln_kernel<<<ROWS, 256, 0, stream>>>(resid, ln1_g, ln1_b, xln);
  gemm128<<<dim3(ROWS / 128, (3 * Dm) / 128), 256, 0, stream>>>(
      xln, qkv_w, qkv_b, big, nullptr, nullptr, nullptr, nullptr, ROWS, 3 * Dm, Dm, 0);
  rope_kernel<<<(ROWS * Hh * (HDd / 2)) / 256, 256, 0, stream>>>(big, rope_cos, rope_sin);
  attn_mfma<<<dim3(Ssz / 64, Hh, Bn), 256, 0, stream>>>(
      big, big + Dm, big + 2 * Dm, aout, 3 * Dm, 3 * Dm, Ssz, 1, scale);
  gemm128<<<dim3(ROWS / 128, Dm / 128), 256, 0, stream>>>(
      aout, out_w, out_b, nullptr, nullptr, resid, resid, nullptr, ROWS, Dm, Dm, 2);

  // ---- cross attention ----
  ln_kernel<<<ROWS, 256, 0, stream>>>(resid, ln2_g, ln2_b, xln);
  gemm128<<<dim3(ROWS / 128, Dm / 128), 256, 0, stream>>>(
      xln, ca_in_w, ca_in_b, qb, nullptr, nullptr, nullptr, nullptr, ROWS, Dm, Dm, 0);
  gemm_bt<<<dim3((Bn * MEMn) / 64, Dm / 64), 256, 0, stream>>>(
      memory, ca_in_w + (size_t)Dm * Dm, ca_in_b + Dm, kb, nullptr, nullptr, nullptr, nullptr,
      Bn * MEMn, Dm, Dm, 0);
  gemm_bt<<<dim3((Bn * MEMn) / 64, Dm / 64), 256, 0, stream>>>(
      memory, ca_in_w + (size_t)2 * Dm * Dm, ca_in_b + 2 * Dm, vb, nullptr, nullptr, nullptr, nullptr,
      Bn * MEMn, Dm, Dm, 0);
  attn_mfma<<<dim3(Ssz / 64, Hh, Bn), 256, 0, stream>>>(
      qb, kb, vb, aout, Dm, Dm, MEMn, 0, scale);
  gemm128<<<dim3(ROWS / 128, Dm / 128), 256, 0, stream>>>(
      aout, ca_out_w, ca_out_b, nullptr, nullptr, resid, resid, nullptr, ROWS, Dm, Dm, 2);

  // ---- FFN ----
  ln_kernel<<<ROWS, 256, 0, stream>>>(resid, ln3_g, ln3_b, xln);
  gemm128<<<dim3(ROWS / 128, DFFn / 128), 256, 0, stream>>>(
      xln, ffn_w1, ffn_b1, big, nullptr, nullptr, nullptr, nullptr, ROWS, DFFn, Dm, 1);
  gemm128<<<dim3(ROWS / 128, Dm / 128), 256, 0, stream>>>(
      big, ffn_w2, ffn_b2, outB, outF, resid, nullptr, flagp, ROWS, Dm, DFFn, 3);
}

// Round 5
// 527.988 us; speedup vs baseline: 1.2443x; 1.1163x over previous
//
#include <hip/hip_runtime.h>
#include <hip/hip_bf16.h>

// PhraseDecoderLayer: B=4,S=1024,D=1024,H=16,HD=64,DFF=4096,MEM=256.
// Round 14: gemm128 -> 512 threads / 8 waves (wave-tile 32x64), depth-3 DMA
// pipeline, 4 rotating buffers (64KB LDS, 2 blocks/CU co-resident).
// Round-13 post-mortem: N=1024 GEMMs (ffn2/out/ca_q/ca_out) run 1 block/CU
// = 1 wave/SIMD -> zero cross-wave overlap; per-step stuck at 1455cy while
// 3-4 block/CU shapes (ffn1/qkv) left the top-5. m114: cross-wave overlap
// is how the MFMA pipe fills; m97's 874TF was at ~3 blocks/CU. 8 waves
// gives 2 waves/SIMD at 1 block/CU. Staging: 1 gload16 of A + 1 of W per
// thread per step (512*16B = 8KB = full 128x32 tile), LDS offset = tid*16.
// vmcnt: 2 loads/step/wave, depth-3 -> steady vmcnt(4), tail 2/0.
// Attention / kv GEMMs / LN / canon unchanged from passing rounds.

using bf16 = __hip_bfloat16;
typedef __bf16 bf16x8 __attribute__((ext_vector_type(8)));
typedef float f32x4 __attribute__((ext_vector_type(4)));

static constexpr int Bn = 4, Ssz = 1024, Dm = 1024, Hh = 16, HDd = 64, DFFn = 4096, MEMn = 256;

__device__ inline float bf2f(bf16 x) { return __bfloat162float(x); }
__device__ inline bf16 f2bf(float x) { return __float2bfloat16(x); }

// async global->LDS, 16B per lane. LDS dest must be linear in tid (wave-uniform
// base + lane*16); caller guarantees &lds byte offset == tid*16 within segment.
__device__ __forceinline__ void gload16(const bf16* g, bf16* l) {
  __builtin_amdgcn_global_load_lds(
      (const __attribute__((address_space(1))) void*)g,
      (__attribute__((address_space(3))) void*)l, 16, 0, 0);
}

// ---------------- dtype detect ----------------
__global__ void detect_kernel(const unsigned* __restrict__ cosw, int* __restrict__ flag) {
  if (threadIdx.x == 0) *flag = (cosw[0] == 0x3F800000u) ? 1 : 0;
}

// ---------------- fused canonicalize: all inputs -> bf16 (+f32 resid for seg0) ----
struct CanonArgs {
  const void* src[23];
  void* dst[23];
  int n[23];  // element count (0 = skip); all counts divisible by 4
};
__global__ __launch_bounds__(256) void canon_all(CanonArgs a, float* __restrict__ resid,
                                                 const int* __restrict__ flagp) {
  const int seg = blockIdx.y;
  const int n4 = a.n[seg] >> 2;
  if (n4 == 0) return;
  const int fl = *flagp;  // wave-uniform
  if (fl) {
    const float4* s = (const float4*)a.src[seg];
    bf16* d = (bf16*)a.dst[seg];
    for (int i = blockIdx.x * 256 + threadIdx.x; i < n4; i += gridDim.x * 256) {
      float4 v = s[i];
      bf16 t[4] = {f2bf(v.x), f2bf(v.y), f2bf(v.z), f2bf(v.w)};
      *reinterpret_cast<unsigned long long*>(d + i * 4) =
          *reinterpret_cast<unsigned long long*>(t);
      if (seg == 0) *reinterpret_cast<float4*>(resid + i * 4) = v;
    }
  } else {
    const unsigned long long* s = (const unsigned long long*)a.src[seg];
    unsigned long long* d = (unsigned long long*)a.dst[seg];
    for (int i = blockIdx.x * 256 + threadIdx.x; i < n4; i += gridDim.x * 256) {
      unsigned long long v = s[i];
      d[i] = v;
      if (seg == 0) {
        const unsigned short* u = reinterpret_cast<const unsigned short*>(&v);
        float4 f;
        f.x = __uint_as_float(((unsigned)u[0]) << 16);
        f.y = __uint_as_float(((unsigned)u[1]) << 16);
        f.z = __uint_as_float(((unsigned)u[2]) << 16);
        f.w = __uint_as_float(((unsigned)u[3]) << 16);
        *reinterpret_cast<float4*>(resid + i * 4) = f;
      }
    }
  }
}

// ---------------- LayerNorm (rows of 1024, fp32 in, bf16 out) ----------------
__global__ __launch_bounds__(256) void ln_kernel(const float* __restrict__ x,
                                                 const bf16* __restrict__ g,
                                                 const bf16* __restrict__ bb,
                                                 bf16* __restrict__ y) {
  const int row = blockIdx.x;
  const float* xr = x + (size_t)row * Dm;
  const int i0 = threadIdx.x * 4;
  float4 v = *reinterpret_cast<const float4*>(xr + i0);
  float s = v.x + v.y + v.z + v.w;
  float ss = v.x * v.x + v.y * v.y + v.z * v.z + v.w * v.w;
#pragma unroll
  for (int o = 32; o > 0; o >>= 1) {
    s += __shfl_down(s, o);
    ss += __shfl_down(ss, o);
  }
  __shared__ float shs[4], shss[4];
  const int wave = threadIdx.x >> 6, lane = threadIdx.x & 63;
  if (lane == 0) { shs[wave] = s; shss[wave] = ss; }
  __syncthreads();
  s = shs[0] + shs[1] + shs[2] + shs[3];
  ss = shss[0] + shss[1] + shss[2] + shss[3];
  const float mu = s * (1.0f / Dm);
  const float var = fmaxf(ss * (1.0f / Dm) - mu * mu, 0.0f);
  const float rs = rsqrtf(var + 1e-5f);
  bf16* yr = y + (size_t)row * Dm + i0;
  float vv[4] = {v.x, v.y, v.z, v.w};
#pragma unroll
  for (int j = 0; j < 4; ++j)
    yr[j] = f2bf((vv[j] - mu) * rs * bf2f(g[i0 + j]) + bf2f(bb[i0 + j]));
}

// ---------------- GEMM 64x64 (round-2 verified; used for M=1024 kv) --------
__global__ __launch_bounds__(256) void gemm_bt(
    const bf16* __restrict__ A, const bf16* __restrict__ W,
    const bf16* __restrict__ bias, bf16* __restrict__ outB, float* __restrict__ outF,
    const float* __restrict__ residIn, float* __restrict__ residOut,
    const int* __restrict__ flagp, int M, int N, int K, int epi) {
  __shared__ bf16 As[64][40];
  __shared__ bf16 Ws[64][40];
  const int tid = threadIdx.x;
  const int m0 = blockIdx.x * 64, n0 = blockIdx.y * 64;
  const int wave = tid >> 6, lane = tid & 63;
  const int wm = wave >> 1, wn = wave & 1;
  const int quad = lane >> 4, m16 = lane & 15;
  const int lr = tid >> 2, lc = (tid & 3) * 8;

  f32x4 acc[2][2] = {};

  const bf16* Ap = A + (size_t)(m0 + lr) * K + lc;
  const bf16* Wp = W + (size_t)(n0 + lr) * K + lc;
  for (int k0 = 0; k0 < K; k0 += 32) {
    float4 av = *reinterpret_cast<const float4*>(Ap + k0);
    float4 wv = *reinterpret_cast<const float4*>(Wp + k0);
    *reinterpret_cast<float4*>(&As[lr][lc]) = av;
    *reinterpret_cast<float4*>(&Ws[lr][lc]) = wv;
    __syncthreads();
    bf16x8 aF[2], bF[2];
#pragma unroll
    for (int t = 0; t < 2; ++t) {
      aF[t] = *reinterpret_cast<const bf16x8*>(&As[wm * 32 + t * 16 + m16][quad * 8]);
      bF[t] = *reinterpret_cast<const bf16x8*>(&Ws[wn * 32 + t * 16 + m16][quad * 8]);
    }
#pragma unroll
    for (int mt = 0; mt < 2; ++mt)
#pragma unroll
      for (int nt = 0; nt < 2; ++nt)
        acc[mt][nt] = __builtin_amdgcn_mfma_f32_16x16x32_bf16(aF[mt], bF[nt], acc[mt][nt], 0, 0, 0);
    __syncthreads();
  }
  const int fl = (epi == 3) ? *flagp : 0;
#pragma unroll
  for (int mt = 0; mt < 2; ++mt) {
#pragma unroll
    for (int nt = 0; nt < 2; ++nt) {
      const int col = n0 + wn * 32 + nt * 16 + m16;
      const float bv = bf2f(bias[col]);
#pragma unroll
      for (int r = 0; r < 4; ++r) {
        const int row = m0 + wm * 32 + mt * 16 + quad * 4 + r;
        const size_t idx = (size_t)row * N + col;
        float v = acc[mt][nt][r] + bv;
        if (epi == 0) {
          outB[idx] = f2bf(v);
        } else if (epi == 1) {
          outB[idx] = f2bf(0.5f * v * (1.0f + erff(v * 0.70710678118654752f)));
        } else if (epi == 2) {
          residOut[idx] = residIn[idx] + v;
        } else {
          const float rr = residIn[idx] + v;
          if (fl) outF[idx] = rr; else outB[idx] = f2bf(rr);
        }
      }
    }
  }
}

// ---------------- GEMM 128x128: 8-wave depth-3 counted-vmcnt DMA pipeline ---
// 512 threads; wave-tile 32x64 (wm=wave>>1, wn=wave&1); acc[2][4].
// 4 rotating LDS buffers (64KB -> 2 blocks/CU). Per K-step t:
//   s_waitcnt vmcnt(4)  (tile t landed; t+1,t+2 in flight)
//   s_barrier
//   6x ds_read_b128 (buf t%4)  [reads first]
//   STAGE tile t+3 -> buf (t+3)%4   (1 gload16 A + 1 gload16 W per thread)
//   8 MFMA
// Tail: 2 peeled steps with vmcnt(2)/(0).
__global__ __launch_bounds__(512) void gemm128(
    const bf16* __restrict__ A, const bf16* __restrict__ W,
    const bf16* __restrict__ bias, bf16* __restrict__ outB, float* __restrict__ outF,
    const float* __restrict__ residIn, float* __restrict__ residOut,
    const int* __restrict__ flagp, int M, int N, int K, int epi) {
  __shared__ bf16 As[4][128][32];
  __shared__ bf16 Ws[4][128][32];
  const int tid = threadIdx.x;
  const int wave = tid >> 6, lane = tid & 63;
  const int wm = wave >> 1;      // 0..3 (32-row group)
  const int wn = wave & 1;       // 0..1 (64-col group)
  const int quad = lane >> 4, m16 = lane & 15;
  const int m0 = blockIdx.x * 128, n0 = blockIdx.y * 128;

  const int sr = tid >> 2;       // 0..127 (tile row)
  const int sc = (tid & 3) * 8;  // 0,8,16,24 (k-col)
  const bf16* Ap = A + (size_t)(m0 + sr) * K + sc;
  const bf16* Wp = W + (size_t)(n0 + sr) * K + sc;

  f32x4 acc[2][4] = {};

#define STAGE128(T, BUF)                                   \
  {                                                        \
    const int kk_ = (T) * 32;                              \
    gload16(Ap + kk_, &As[BUF][sr][sc]);                   \
    gload16(Wp + kk_, &Ws[BUF][sr][sc]);                   \
  }

#define READS128(RB)                                                                        \
  _Pragma("unroll") for (int tt = 0; tt < 2; ++tt)                                          \
    aF[tt] = *reinterpret_cast<const bf16x8*>(&As[RB][wm * 32 + tt * 16 + m16][quad * 8]);  \
  _Pragma("unroll") for (int nt = 0; nt < 4; ++nt)                                          \
    bF[nt] = *reinterpret_cast<const bf16x8*>(&Ws[RB][wn * 64 + nt * 16 + m16][quad * 8]);

#define MFMAS128                                                                            \
  _Pragma("unroll") for (int mt = 0; mt < 2; ++mt)                                          \
  _Pragma("unroll") for (int nt = 0; nt < 4; ++nt)                                          \
    acc[mt][nt] = __builtin_amdgcn_mfma_f32_16x16x32_bf16(aF[mt], bF[nt], acc[mt][nt], 0, 0, 0);

  const int nsteps = K >> 5;  // K=1024 or 4096 -> 32 or 128 steps
  STAGE128(0, 0)
  STAGE128(1, 1)
  STAGE128(2, 2)

  int rb = 0, sb = 3;
  for (int t = 0; t < nsteps - 2; ++t) {
    asm volatile("s_waitcnt vmcnt(4)" ::: "memory");
    __builtin_amdgcn_s_barrier();
    __builtin_amdgcn_sched_barrier(0);
    bf16x8 aF[2], bF[4];
    READS128(rb)
    __builtin_amdgcn_sched_barrier(0);
    if (t + 3 < nsteps) { STAGE128(t + 3, sb) }
    __builtin_amdgcn_sched_barrier(0);
    MFMAS128
    rb = (rb + 1 == 4) ? 0 : rb + 1;
    sb = (sb + 1 == 4) ? 0 : sb + 1;
  }
  {  // t = nsteps-2: outstanding tiles {t, t+1} = 4 loads -> wait 2 = tile t
    asm volatile("s_waitcnt vmcnt(2)" ::: "memory");
    __builtin_amdgcn_s_barrier();
    __builtin_amdgcn_sched_barrier(0);
    bf16x8 aF[2], bF[4];
    READS128(rb)
    MFMAS128
    rb = (rb + 1 == 4) ? 0 : rb + 1;
  }
  {  // t = nsteps-1
    asm volatile("s_waitcnt vmcnt(0)" ::: "memory");
    __builtin_amdgcn_s_barrier();
    __builtin_amdgcn_sched_barrier(0);
    bf16x8 aF[2], bF[4];
    READS128(rb)
    MFMAS128
  }
#undef STAGE128
#undef READS128
#undef MFMAS128

  const int fl = (epi == 3) ? *flagp : 0;
  // C/D layout: col = lane&15, row = quad*4 + reg
#pragma unroll
  for (int mt = 0; mt < 2; ++mt) {
#pragma unroll
    for (int nt = 0; nt < 4; ++nt) {
      const int col = n0 + wn * 64 + nt * 16 + m16;
      const float bv = bf2f(bias[col]);
#pragma unroll
      for (int r = 0; r < 4; ++r) {
        const int row = m0 + wm * 32 + mt * 16 + quad * 4 + r;
        const size_t idx = (size_t)row * N + col;
        float v = acc[mt][nt][r] + bv;
        if (epi == 0) {
          outB[idx] = f2bf(v);
        } else if (epi == 1) {
          outB[idx] = f2bf(0.5f * v * (1.0f + erff(v * 0.70710678118654752f)));
        } else if (epi == 2) {
          residOut[idx] = residIn[idx] + v;
        } else {
          const float rr = residIn[idx] + v;
          if (fl) outF[idx] = rr; else outB[idx] = f2bf(rr);
        }
      }
    }
  }
}

// ---------------- RoPE in-place on qkv buffer [4096, 3072] ----------------
__global__ __launch_bounds__(256) void rope_kernel(bf16* __restrict__ qkv,
                                                   const bf16* __restrict__ cosb,
                                                   const bf16* __restrict__ sinb) {
  const int idx = blockIdx.x * 256 + threadIdx.x;  // over 4096*16*32
  const int i = idx & 31;
  const int h = (idx >> 5) & 15;
  const int r = idx >> 9;
  const int s = r & (Ssz - 1);
  const float c = bf2f(cosb[s * 32 + i]);
  const float sn = bf2f(sinb[s * 32 + i]);
  bf16* base = qkv + (size_t)r * (3 * Dm) + h * 64 + 2 * i;
  float x0 = bf2f(base[0]), x1 = bf2f(base[1]);
  base[0] = f2bf(x0 * c - x1 * sn);
  base[1] = f2bf(x0 * sn + x1 * c);
  x0 = bf2f(base[Dm]); x1 = bf2f(base[Dm + 1]);
  base[Dm] = f2bf(x0 * c - x1 * sn);
  base[Dm + 1] = f2bf(x0 * sn + x1 * c);
}

// ---------------- MFMA flash attention (round-3 verified) ----------------
__global__ __launch_bounds__(256) void attn_mfma(
    const bf16* __restrict__ Qb, const bf16* __restrict__ Kb, const bf16* __restrict__ Vb,
    bf16* __restrict__ Ob, int qStride, int kvStride, int kvLen, int causal, float scale) {
  __shared__ bf16 Ks[64][72];
  __shared__ bf16 Vt[64][72];
  __shared__ bf16 Ps[64][72];
  const int tid = threadIdx.x;
  const int wave = tid >> 6, lane = tid & 63;
  const int quad = lane >> 4, m16 = lane & 15;
  const int b = blockIdx.z, h = blockIdx.y;
  const int q0 = blockIdx.x * 64;
  const int sr = tid >> 2, sc = (tid & 3) * 16;

  {
    const bf16* qp = Qb + (size_t)(b * Ssz + q0 + sr) * qStride + h * 64 + sc;
    float4 a = reinterpret_cast<const float4*>(qp)[0];
    float4 bb2 = reinterpret_cast<const float4*>(qp)[1];
    *reinterpret_cast<float4*>(&Ps[sr][sc]) = a;
    *reinterpret_cast<float4*>(&Ps[sr][sc + 8]) = bb2;
  }
  __syncthreads();
  bf16x8 qf[2];
  qf[0] = *reinterpret_cast<const bf16x8*>(&Ps[wave * 16 + m16][quad * 8]);
  qf[1] = *reinterpret_cast<const bf16x8*>(&Ps[wave * 16 + m16][32 + quad * 8]);

  f32x4 oacc[4] = {};
  float mrow[4], lrow[4];
#pragma unroll
  for (int r = 0; r < 4; ++r) { mrow[r] = -30000.0f; lrow[r] = 0.0f; }

  const int nk = causal ? (q0 + 64) : kvLen;
  for (int kt = 0; kt < nk; kt += 64) {
    {
      const bf16* kp = Kb + (size_t)(b * kvLen + kt + sr) * kvStride + h * 64 + sc;
      float4 k1 = reinterpret_cast<const float4*>(kp)[0];
      float4 k2 = reinterpret_cast<const float4*>(kp)[1];
      *reinterpret_cast<float4*>(&Ks[sr][sc]) = k1;
      *reinterpret_cast<float4*>(&Ks[sr][sc + 8]) = k2;
      const bf16* vp = Vb + (size_t)(b * kvLen + kt + sr) * kvStride + h * 64 + sc;
      float4 v1 = reinterpret_cast<const float4*>(vp)[0];
      float4 v2 = reinterpret_cast<const float4*>(vp)[1];
      const bf16* tv1 = reinterpret_cast<const bf16*>(&v1);
      const bf16* tv2 = reinterpret_cast<const bf16*>(&v2);
#pragma unroll
      for (int j = 0; j < 8; ++j) {
        Vt[sc + j][sr] = tv1[j];
        Vt[sc + 8 + j][sr] = tv2[j];
      }
    }
    __syncthreads();

    f32x4 sacc[4] = {};
#pragma unroll
    for (int nt = 0; nt < 4; ++nt) {
      bf16x8 kf0 = *reinterpret_cast<const bf16x8*>(&Ks[nt * 16 + m16][quad * 8]);
      bf16x8 kf1 = *reinterpret_cast<const bf16x8*>(&Ks[nt * 16 + m16][32 + quad * 8]);
      sacc[nt] = __builtin_amdgcn_mfma_f32_16x16x32_bf16(qf[0], kf0, sacc[nt], 0, 0, 0);
      sacc[nt] = __builtin_amdgcn_mfma_f32_16x16x32_bf16(qf[1], kf1, sacc[nt], 0, 0, 0);
    }
    const bool dmask = (causal != 0) && (kt == q0);
#pragma unroll
    for (int nt = 0; nt < 4; ++nt) {
#pragma unroll
      for (int r = 0; r < 4; ++r) {
        float s = sacc[nt][r] * scale;
        if (dmask && (nt * 16 + m16 > wave * 16 + quad * 4 + r)) s = -30000.0f;
        sacc[nt][r] = s;
      }
    }

#pragma unroll
    for (int r = 0; r < 4; ++r) {
      float mx = fmaxf(fmaxf(sacc[0][r], sacc[1][r]), fmaxf(sacc[2][r], sacc[3][r]));
#pragma unroll
      for (int off = 1; off < 16; off <<= 1) mx = fmaxf(mx, __shfl_xor(mx, off));
      const float mn = fmaxf(mrow[r], mx);
      const float corr = __expf(mrow[r] - mn);
      mrow[r] = mn;
      float psum = 0.0f;
#pragma unroll
      for (int nt = 0; nt < 4; ++nt) {
        const float p = __expf(sacc[nt][r] - mn);
        sacc[nt][r] = p;
        psum += p;
      }
#pragma unroll
      for (int off = 1; off < 16; off <<= 1) psum += __shfl_xor(psum, off);
      lrow[r] = lrow[r] * corr + psum;
#pragma unroll
      for (int nt = 0; nt < 4; ++nt) oacc[nt][r] *= corr;
#pragma unroll
      for (int nt = 0; nt < 4; ++nt)
        Ps[wave * 16 + quad * 4 + r][nt * 16 + m16] = f2bf(sacc[nt][r]);
    }
    bf16x8 pf0 = *reinterpret_cast<const bf16x8*>(&Ps[wave * 16 + m16][quad * 8]);
    bf16x8 pf1 = *reinterpret_cast<const bf16x8*>(&Ps[wave * 16 + m16][32 + quad * 8]);
#pragma unroll
    for (int nt = 0; nt < 4; ++nt) {
      bf16x8 vf0 = *reinterpret_cast<const bf16x8*>(&Vt[nt * 16 + m16][quad * 8]);
      bf16x8 vf1 = *reinterpret_cast<const bf16x8*>(&Vt[nt * 16 + m16][32 + quad * 8]);
      oacc[nt] = __builtin_amdgcn_mfma_f32_16x16x32_bf16(pf0, vf0, oacc[nt], 0, 0, 0);
      oacc[nt] = __builtin_amdgcn_mfma_f32_16x16x32_bf16(pf1, vf1, oacc[nt], 0, 0, 0);
    }
    __syncthreads();
  }

  float inv[4];
#pragma unroll
  for (int r = 0; r < 4; ++r) inv[r] = 1.0f / lrow[r];
#pragma unroll
  for (int r = 0; r < 4; ++r) {
    bf16* op = Ob + (size_t)(b * Ssz + q0 + wave * 16 + quad * 4 + r) * Dm + h * 64 + m16;
#pragma unroll
    for (int nt = 0; nt < 4; ++nt) op[nt * 16] = f2bf(oacc[nt][r] * inv[r]);
  }
}

extern "C" void kernel_launch(void* const* d_in, const int* in_sizes, int n_in,
                              void* d_out, int out_size, void* d_ws, size_t ws_size,
                              hipStream_t stream) {
  char* ws = (char*)d_ws;
  int* flagp   = (int*)ws;                          // [0,1MB) control
  float* resid = (float*)(ws + (1ull << 20));       // 16MB fp32 residual
  bf16* xln    = (bf16*)(ws + (17ull << 20));       // 8MB LN output
  bf16* aout   = (bf16*)(ws + (25ull << 20));       // 8MB attn out
  bf16* big    = (bf16*)(ws + (33ull << 20));       // 32MB: qkv | qb | ffn1
  size_t off   = (65ull << 20);                     // canonical bf16 inputs

  detect_kernel<<<1, 64, 0, stream>>>((const unsigned*)d_in[3], flagp);

  CanonArgs ca;
  bf16* c[23];
  for (int i = 0; i < 23; ++i) {
    if (i == 2) { c[i] = nullptr; ca.src[i] = d_in[i]; ca.dst[i] = nullptr; ca.n[i] = 0; continue; }
    c[i] = (bf16*)(ws + off);
    const int n = in_sizes[i];
    off += ((size_t)n * 2 + 255) & ~(size_t)255;
    ca.src[i] = d_in[i];
    ca.dst[i] = c[i];
    ca.n[i] = n;
  }
  canon_all<<<dim3(256, 23), 256, 0, stream>>>(ca, resid, flagp);

  const bf16 *memory = c[1], *rope_cos = c[3], *rope_sin = c[4];
  const bf16 *qkv_w = c[5], *qkv_b = c[6], *out_w = c[7], *out_b = c[8];
  const bf16 *ca_in_w = c[9], *ca_in_b = c[10], *ca_out_w = c[11], *ca_out_b = c[12];
  const bf16 *ffn_w1 = c[13], *ffn_b1 = c[14], *ffn_w2 = c[15], *ffn_b2 = c[16];
  const bf16 *ln1_g = c[17], *ln1_b = c[18], *ln2_g = c[19], *ln2_b = c[20];
  const bf16 *ln3_g = c[21], *ln3_b = c[22];

  bf16* qb = big;
  bf16* kb = (bf16*)(ws + (41ull << 20));
  bf16* vb = (bf16*)(ws + (43ull << 20));
  bf16* outB = (bf16*)d_out;
  float* outF = (float*)d_out;

  const int ROWS = Bn * Ssz;   // 4096
  const float scale = 0.125f;  // 1/sqrt(64)

  // ---- self attention ----
  ln_kernel<<<ROWS, 256, 0, stream>>>(resid, ln1_g, ln1_b, xln);
  gemm128<<<dim3(ROWS / 128, (3 * Dm) / 128), 512, 0, stream>>>(
      xln, qkv_w, qkv_b, big, nullptr, nullptr, nullptr, nullptr, ROWS, 3 * Dm, Dm, 0);
  rope_kernel<<<(ROWS * Hh * (HDd / 2)) / 256, 256, 0, stream>>>(big, rope_cos, rope_sin);
  attn_mfma<<<dim3(Ssz / 64, Hh, Bn), 256, 0, stream>>>(
      big, big + Dm, big + 2 * Dm, aout, 3 * Dm, 3 * Dm, Ssz, 1, scale);
  gemm128<<<dim3(ROWS / 128, Dm / 128), 512, 0, stream>>>(
      aout, out_w, out_b, nullptr, nullptr, resid, resid, nullptr, ROWS, Dm, Dm, 2);

  // ---- cross attention ----
  ln_kernel<<<ROWS, 256, 0, stream>>>(resid, ln2_g, ln2_b, xln);
  gemm128<<<dim3(ROWS / 128, Dm / 128), 512, 0, stream>>>(
      xln, ca_in_w, ca_in_b, qb, nullptr, nullptr, nullptr, nullptr, ROWS, Dm, Dm, 0);
  gemm_bt<<<dim3((Bn * MEMn) / 64, Dm / 64), 256, 0, stream>>>(
      memory, ca_in_w + (size_t)Dm * Dm, ca_in_b + Dm, kb, nullptr, nullptr, nullptr, nullptr,
      Bn * MEMn, Dm, Dm, 0);
  gemm_bt<<<dim3((Bn * MEMn) / 64, Dm / 64), 256, 0, stream>>>(
      memory, ca_in_w + (size_t)2 * Dm * Dm, ca_in_b + 2 * Dm, vb, nullptr, nullptr, nullptr, nullptr,
      Bn * MEMn, Dm, Dm, 0);
  attn_mfma<<<dim3(Ssz / 64, Hh, Bn), 256, 0, stream>>>(
      qb, kb, vb, aout, Dm, Dm, MEMn, 0, scale);
  gemm128<<<dim3(ROWS / 128, Dm / 128), 512, 0, stream>>>(
      aout, ca_out_w, ca_out_b, nullptr, nullptr, resid, resid, nullptr, ROWS, Dm, Dm, 2);

  // ---- FFN ----
  ln_kernel<<<ROWS, 256, 0, stream>>>(resid, ln3_g, ln3_b, xln);
  gemm128<<<dim3(ROWS / 128, DFFn / 128), 512, 0, stream>>>(
      xln, ffn_w1, ffn_b1, big, nullptr, nullptr, nullptr, nullptr, ROWS, DFFn, Dm, 1);
  gemm128<<<dim3(ROWS / 128, Dm / 128), 512, 0, stream>>>(
      big, ffn_w2, ffn_b2, outB, outF, resid, nullptr, flagp, ROWS, Dm, DFFn, 3);
}

// Round 7
// 519.562 us; speedup vs baseline: 1.2645x; 1.0162x over previous
//
#include <hip/hip_runtime.h>
#include <hip/hip_bf16.h>

// PhraseDecoderLayer: B=4,S=1024,D=1024,H=16,HD=64,DFF=4096,MEM=256.
// Round 16: identical to round 15 (bench was an infra flake — container
// acquisition failed twice; no counter or correctness evidence).
// attn_mfma = 8 waves / 512 threads / 128-row Q tile (KV tile 64); halves
// staged K/V bytes + barriers per Q-row; V-transpose store wave-per-d-block
// (2-way banks = free); per-wave live-guard skips compute past the causal
// diagonal (barriers uniform). gemm128 = 8-wave depth-3 counted-vmcnt DMA
// pipeline. gemm_bt / LN / canon unchanged from passing rounds.

using bf16 = __hip_bfloat16;
typedef __bf16 bf16x8 __attribute__((ext_vector_type(8)));
typedef float f32x4 __attribute__((ext_vector_type(4)));

static constexpr int Bn = 4, Ssz = 1024, Dm = 1024, Hh = 16, HDd = 64, DFFn = 4096, MEMn = 256;

__device__ inline float bf2f(bf16 x) { return __bfloat162float(x); }
__device__ inline bf16 f2bf(float x) { return __float2bfloat16(x); }

// async global->LDS, 16B per lane. LDS dest must be linear in tid (wave-uniform
// base + lane*16); caller guarantees &lds byte offset == tid*16 within segment.
__device__ __forceinline__ void gload16(const bf16* g, bf16* l) {
  __builtin_amdgcn_global_load_lds(
      (const __attribute__((address_space(1))) void*)g,
      (__attribute__((address_space(3))) void*)l, 16, 0, 0);
}

// ---------------- dtype detect ----------------
__global__ void detect_kernel(const unsigned* __restrict__ cosw, int* __restrict__ flag) {
  if (threadIdx.x == 0) *flag = (cosw[0] == 0x3F800000u) ? 1 : 0;
}

// ---------------- fused canonicalize: all inputs -> bf16 (+f32 resid for seg0) ----
struct CanonArgs {
  const void* src[23];
  void* dst[23];
  int n[23];  // element count (0 = skip); all counts divisible by 4
};
__global__ __launch_bounds__(256) void canon_all(CanonArgs a, float* __restrict__ resid,
                                                 const int* __restrict__ flagp) {
  const int seg = blockIdx.y;
  const int n4 = a.n[seg] >> 2;
  if (n4 == 0) return;
  const int fl = *flagp;  // wave-uniform
  if (fl) {
    const float4* s = (const float4*)a.src[seg];
    bf16* d = (bf16*)a.dst[seg];
    for (int i = blockIdx.x * 256 + threadIdx.x; i < n4; i += gridDim.x * 256) {
      float4 v = s[i];
      bf16 t[4] = {f2bf(v.x), f2bf(v.y), f2bf(v.z), f2bf(v.w)};
      *reinterpret_cast<unsigned long long*>(d + i * 4) =
          *reinterpret_cast<unsigned long long*>(t);
      if (seg == 0) *reinterpret_cast<float4*>(resid + i * 4) = v;
    }
  } else {
    const unsigned long long* s = (const unsigned long long*)a.src[seg];
    unsigned long long* d = (unsigned long long*)a.dst[seg];
    for (int i = blockIdx.x * 256 + threadIdx.x; i < n4; i += gridDim.x * 256) {
      unsigned long long v = s[i];
      d[i] = v;
      if (seg == 0) {
        const unsigned short* u = reinterpret_cast<const unsigned short*>(&v);
        float4 f;
        f.x = __uint_as_float(((unsigned)u[0]) << 16);
        f.y = __uint_as_float(((unsigned)u[1]) << 16);
        f.z = __uint_as_float(((unsigned)u[2]) << 16);
        f.w = __uint_as_float(((unsigned)u[3]) << 16);
        *reinterpret_cast<float4*>(resid + i * 4) = f;
      }
    }
  }
}

// ---------------- LayerNorm (rows of 1024, fp32 in, bf16 out) ----------------
__global__ __launch_bounds__(256) void ln_kernel(const float* __restrict__ x,
                                                 const bf16* __restrict__ g,
                                                 const bf16* __restrict__ bb,
                                                 bf16* __restrict__ y) {
  const int row = blockIdx.x;
  const float* xr = x + (size_t)row * Dm;
  const int i0 = threadIdx.x * 4;
  float4 v = *reinterpret_cast<const float4*>(xr + i0);
  float s = v.x + v.y + v.z + v.w;
  float ss = v.x * v.x + v.y * v.y + v.z * v.z + v.w * v.w;
#pragma unroll
  for (int o = 32; o > 0; o >>= 1) {
    s += __shfl_down(s, o);
    ss += __shfl_down(ss, o);
  }
  __shared__ float shs[4], shss[4];
  const int wave = threadIdx.x >> 6, lane = threadIdx.x & 63;
  if (lane == 0) { shs[wave] = s; shss[wave] = ss; }
  __syncthreads();
  s = shs[0] + shs[1] + shs[2] + shs[3];
  ss = shss[0] + shss[1] + shss[2] + shss[3];
  const float mu = s * (1.0f / Dm);
  const float var = fmaxf(ss * (1.0f / Dm) - mu * mu, 0.0f);
  const float rs = rsqrtf(var + 1e-5f);
  bf16* yr = y + (size_t)row * Dm + i0;
  float vv[4] = {v.x, v.y, v.z, v.w};
#pragma unroll
  for (int j = 0; j < 4; ++j)
    yr[j] = f2bf((vv[j] - mu) * rs * bf2f(g[i0 + j]) + bf2f(bb[i0 + j]));
}

// ---------------- GEMM 64x64 (round-2 verified; used for M=1024 kv) --------
__global__ __launch_bounds__(256) void gemm_bt(
    const bf16* __restrict__ A, const bf16* __restrict__ W,
    const bf16* __restrict__ bias, bf16* __restrict__ outB, float* __restrict__ outF,
    const float* __restrict__ residIn, float* __restrict__ residOut,
    const int* __restrict__ flagp, int M, int N, int K, int epi) {
  __shared__ bf16 As[64][40];
  __shared__ bf16 Ws[64][40];
  const int tid = threadIdx.x;
  const int m0 = blockIdx.x * 64, n0 = blockIdx.y * 64;
  const int wave = tid >> 6, lane = tid & 63;
  const int wm = wave >> 1, wn = wave & 1;
  const int quad = lane >> 4, m16 = lane & 15;
  const int lr = tid >> 2, lc = (tid & 3) * 8;

  f32x4 acc[2][2] = {};

  const bf16* Ap = A + (size_t)(m0 + lr) * K + lc;
  const bf16* Wp = W + (size_t)(n0 + lr) * K + lc;
  for (int k0 = 0; k0 < K; k0 += 32) {
    float4 av = *reinterpret_cast<const float4*>(Ap + k0);
    float4 wv = *reinterpret_cast<const float4*>(Wp + k0);
    *reinterpret_cast<float4*>(&As[lr][lc]) = av;
    *reinterpret_cast<float4*>(&Ws[lr][lc]) = wv;
    __syncthreads();
    bf16x8 aF[2], bF[2];
#pragma unroll
    for (int t = 0; t < 2; ++t) {
      aF[t] = *reinterpret_cast<const bf16x8*>(&As[wm * 32 + t * 16 + m16][quad * 8]);
      bF[t] = *reinterpret_cast<const bf16x8*>(&Ws[wn * 32 + t * 16 + m16][quad * 8]);
    }
#pragma unroll
    for (int mt = 0; mt < 2; ++mt)
#pragma unroll
      for (int nt = 0; nt < 2; ++nt)
        acc[mt][nt] = __builtin_amdgcn_mfma_f32_16x16x32_bf16(aF[mt], bF[nt], acc[mt][nt], 0, 0, 0);
    __syncthreads();
  }
  const int fl = (epi == 3) ? *flagp : 0;
#pragma unroll
  for (int mt = 0; mt < 2; ++mt) {
#pragma unroll
    for (int nt = 0; nt < 2; ++nt) {
      const int col = n0 + wn * 32 + nt * 16 + m16;
      const float bv = bf2f(bias[col]);
#pragma unroll
      for (int r = 0; r < 4; ++r) {
        const int row = m0 + wm * 32 + mt * 16 + quad * 4 + r;
        const size_t idx = (size_t)row * N + col;
        float v = acc[mt][nt][r] + bv;
        if (epi == 0) {
          outB[idx] = f2bf(v);
        } else if (epi == 1) {
          outB[idx] = f2bf(0.5f * v * (1.0f + erff(v * 0.70710678118654752f)));
        } else if (epi == 2) {
          residOut[idx] = residIn[idx] + v;
        } else {
          const float rr = residIn[idx] + v;
          if (fl) outF[idx] = rr; else outB[idx] = f2bf(rr);
        }
      }
    }
  }
}

// ---------------- GEMM 128x128: 8-wave depth-3 counted-vmcnt DMA pipeline ---
// 512 threads; wave-tile 32x64 (wm=wave>>1, wn=wave&1); acc[2][4].
// 4 rotating LDS buffers (64KB -> 2 blocks/CU). Per K-step t:
//   s_waitcnt vmcnt(4) -> s_barrier -> 6x ds_read_b128 (buf t%4) ->
//   STAGE tile t+3 -> 8 MFMA.  Tail: 2 peeled steps with vmcnt(2)/(0).
__global__ __launch_bounds__(512) void gemm128(
    const bf16* __restrict__ A, const bf16* __restrict__ W,
    const bf16* __restrict__ bias, bf16* __restrict__ outB, float* __restrict__ outF,
    const float* __restrict__ residIn, float* __restrict__ residOut,
    const int* __restrict__ flagp, int M, int N, int K, int epi) {
  __shared__ bf16 As[4][128][32];
  __shared__ bf16 Ws[4][128][32];
  const int tid = threadIdx.x;
  const int wave = tid >> 6, lane = tid & 63;
  const int wm = wave >> 1;      // 0..3 (32-row group)
  const int wn = wave & 1;       // 0..1 (64-col group)
  const int quad = lane >> 4, m16 = lane & 15;
  const int m0 = blockIdx.x * 128, n0 = blockIdx.y * 128;

  const int sr = tid >> 2;       // 0..127 (tile row)
  const int sc = (tid & 3) * 8;  // 0,8,16,24 (k-col)
  const bf16* Ap = A + (size_t)(m0 + sr) * K + sc;
  const bf16* Wp = W + (size_t)(n0 + sr) * K + sc;

  f32x4 acc[2][4] = {};

#define STAGE128(T, BUF)                                   \
  {                                                        \
    const int kk_ = (T) * 32;                              \
    gload16(Ap + kk_, &As[BUF][sr][sc]);                   \
    gload16(Wp + kk_, &Ws[BUF][sr][sc]);                   \
  }

#define READS128(RB)                                                                        \
  _Pragma("unroll") for (int tt = 0; tt < 2; ++tt)                                          \
    aF[tt] = *reinterpret_cast<const bf16x8*>(&As[RB][wm * 32 + tt * 16 + m16][quad * 8]);  \
  _Pragma("unroll") for (int nt = 0; nt < 4; ++nt)                                          \
    bF[nt] = *reinterpret_cast<const bf16x8*>(&Ws[RB][wn * 64 + nt * 16 + m16][quad * 8]);

#define MFMAS128                                                                            \
  _Pragma("unroll") for (int mt = 0; mt < 2; ++mt)                                          \
  _Pragma("unroll") for (int nt = 0; nt < 4; ++nt)                                          \
    acc[mt][nt] = __builtin_amdgcn_mfma_f32_16x16x32_bf16(aF[mt], bF[nt], acc[mt][nt], 0, 0, 0);

  const int nsteps = K >> 5;  // K=1024 or 4096 -> 32 or 128 steps
  STAGE128(0, 0)
  STAGE128(1, 1)
  STAGE128(2, 2)

  int rb = 0, sb = 3;
  for (int t = 0; t < nsteps - 2; ++t) {
    asm volatile("s_waitcnt vmcnt(4)" ::: "memory");
    __builtin_amdgcn_s_barrier();
    __builtin_amdgcn_sched_barrier(0);
    bf16x8 aF[2], bF[4];
    READS128(rb)
    __builtin_amdgcn_sched_barrier(0);
    if (t + 3 < nsteps) { STAGE128(t + 3, sb) }
    __builtin_amdgcn_sched_barrier(0);
    MFMAS128
    rb = (rb + 1 == 4) ? 0 : rb + 1;
    sb = (sb + 1 == 4) ? 0 : sb + 1;
  }
  {  // t = nsteps-2: outstanding tiles {t, t+1} = 4 loads -> wait 2 = tile t
    asm volatile("s_waitcnt vmcnt(2)" ::: "memory");
    __builtin_amdgcn_s_barrier();
    __builtin_amdgcn_sched_barrier(0);
    bf16x8 aF[2], bF[4];
    READS128(rb)
    MFMAS128
    rb = (rb + 1 == 4) ? 0 : rb + 1;
  }
  {  // t = nsteps-1
    asm volatile("s_waitcnt vmcnt(0)" ::: "memory");
    __builtin_amdgcn_s_barrier();
    __builtin_amdgcn_sched_barrier(0);
    bf16x8 aF[2], bF[4];
    READS128(rb)
    MFMAS128
  }
#undef STAGE128
#undef READS128
#undef MFMAS128

  const int fl = (epi == 3) ? *flagp : 0;
  // C/D layout: col = lane&15, row = quad*4 + reg
#pragma unroll
  for (int mt = 0; mt < 2; ++mt) {
#pragma unroll
    for (int nt = 0; nt < 4; ++nt) {
      const int col = n0 + wn * 64 + nt * 16 + m16;
      const float bv = bf2f(bias[col]);
#pragma unroll
      for (int r = 0; r < 4; ++r) {
        const int row = m0 + wm * 32 + mt * 16 + quad * 4 + r;
        const size_t idx = (size_t)row * N + col;
        float v = acc[mt][nt][r] + bv;
        if (epi == 0) {
          outB[idx] = f2bf(v);
        } else if (epi == 1) {
          outB[idx] = f2bf(0.5f * v * (1.0f + erff(v * 0.70710678118654752f)));
        } else if (epi == 2) {
          residOut[idx] = residIn[idx] + v;
        } else {
          const float rr = residIn[idx] + v;
          if (fl) outF[idx] = rr; else outB[idx] = f2bf(rr);
        }
      }
    }
  }
}

// ---------------- RoPE in-place on qkv buffer [4096, 3072] ----------------
__global__ __launch_bounds__(256) void rope_kernel(bf16* __restrict__ qkv,
                                                   const bf16* __restrict__ cosb,
                                                   const bf16* __restrict__ sinb) {
  const int idx = blockIdx.x * 256 + threadIdx.x;  // over 4096*16*32
  const int i = idx & 31;
  const int h = (idx >> 5) & 15;
  const int r = idx >> 9;
  const int s = r & (Ssz - 1);
  const float c = bf2f(cosb[s * 32 + i]);
  const float sn = bf2f(sinb[s * 32 + i]);
  bf16* base = qkv + (size_t)r * (3 * Dm) + h * 64 + 2 * i;
  float x0 = bf2f(base[0]), x1 = bf2f(base[1]);
  base[0] = f2bf(x0 * c - x1 * sn);
  base[1] = f2bf(x0 * sn + x1 * c);
  x0 = bf2f(base[Dm]); x1 = bf2f(base[Dm + 1]);
  base[Dm] = f2bf(x0 * c - x1 * sn);
  base[Dm + 1] = f2bf(x0 * sn + x1 * c);
}

// ---------------- MFMA flash attention: 8 waves, 128-row Q tile ----------------
// Per block: Q rows q0..q0+127 (wave w owns rows q0+16w..+15). KV tile = 64.
// Staging (all 512 threads): K row=lane, dbase=8*wave (float4); V same rows,
// transposed store Vt[8w+j][lane] (2-way banks = free). live-guard: waves
// past their causal diagonal skip compute but hit both barriers.
__global__ __launch_bounds__(512) void attn_mfma(
    const bf16* __restrict__ Qb, const bf16* __restrict__ Kb, const bf16* __restrict__ Vb,
    bf16* __restrict__ Ob, int qStride, int kvStride, int kvLen, int causal, float scale) {
  __shared__ bf16 Ks[64][72];
  __shared__ bf16 Vt[64][72];
  __shared__ bf16 Ps[128][72];
  const int tid = threadIdx.x;
  const int wave = tid >> 6, lane = tid & 63;
  const int quad = lane >> 4, m16 = lane & 15;
  const int b = blockIdx.z, h = blockIdx.y;
  const int q0 = blockIdx.x * 128;

  {  // Q staging: 512 thr x 32B = 16KB
    const int sr = tid >> 2, sc = (tid & 3) * 16;
    const bf16* qp = Qb + (size_t)(b * Ssz + q0 + sr) * qStride + h * 64 + sc;
    float4 a = reinterpret_cast<const float4*>(qp)[0];
    float4 bb2 = reinterpret_cast<const float4*>(qp)[1];
    *reinterpret_cast<float4*>(&Ps[sr][sc]) = a;
    *reinterpret_cast<float4*>(&Ps[sr][sc + 8]) = bb2;
  }
  __syncthreads();
  bf16x8 qf[2];
  qf[0] = *reinterpret_cast<const bf16x8*>(&Ps[wave * 16 + m16][quad * 8]);
  qf[1] = *reinterpret_cast<const bf16x8*>(&Ps[wave * 16 + m16][32 + quad * 8]);

  f32x4 oacc[4] = {};
  float mrow[4], lrow[4];
#pragma unroll
  for (int r = 0; r < 4; ++r) { mrow[r] = -30000.0f; lrow[r] = 0.0f; }

  const int wrow0 = q0 + wave * 16;  // this wave's first q row
  const int nk = causal ? (q0 + 128) : kvLen;
  for (int kt = 0; kt < nk; kt += 64) {
    {  // K/V staging: row = lane, d-block = 8*wave
      const int dbase = wave * 8;
      const bf16* kp = Kb + (size_t)(b * kvLen + kt + lane) * kvStride + h * 64 + dbase;
      float4 k1 = *reinterpret_cast<const float4*>(kp);
      *reinterpret_cast<float4*>(&Ks[lane][dbase]) = k1;
      const bf16* vp = Vb + (size_t)(b * kvLen + kt + lane) * kvStride + h * 64 + dbase;
      float4 v1 = *reinterpret_cast<const float4*>(vp);
      const bf16* tv = reinterpret_cast<const bf16*>(&v1);
#pragma unroll
      for (int j = 0; j < 8; ++j) Vt[dbase + j][lane] = tv[j];
    }
    __syncthreads();

    const bool live = (causal == 0) || (kt <= wrow0 + 15);
    if (live) {
      f32x4 sacc[4] = {};
#pragma unroll
      for (int nt = 0; nt < 4; ++nt) {
        bf16x8 kf0 = *reinterpret_cast<const bf16x8*>(&Ks[nt * 16 + m16][quad * 8]);
        bf16x8 kf1 = *reinterpret_cast<const bf16x8*>(&Ks[nt * 16 + m16][32 + quad * 8]);
        sacc[nt] = __builtin_amdgcn_mfma_f32_16x16x32_bf16(qf[0], kf0, sacc[nt], 0, 0, 0);
        sacc[nt] = __builtin_amdgcn_mfma_f32_16x16x32_bf16(qf[1], kf1, sacc[nt], 0, 0, 0);
      }
      const bool dmask = (causal != 0) && (kt + 63 > wrow0);
#pragma unroll
      for (int nt = 0; nt < 4; ++nt) {
#pragma unroll
        for (int r = 0; r < 4; ++r) {
          float s = sacc[nt][r] * scale;
          if (dmask && (kt + nt * 16 + m16 > wrow0 + quad * 4 + r)) s = -30000.0f;
          sacc[nt][r] = s;
        }
      }

#pragma unroll
      for (int r = 0; r < 4; ++r) {
        float mx = fmaxf(fmaxf(sacc[0][r], sacc[1][r]), fmaxf(sacc[2][r], sacc[3][r]));
#pragma unroll
        for (int off = 1; off < 16; off <<= 1) mx = fmaxf(mx, __shfl_xor(mx, off));
        const float mn = fmaxf(mrow[r], mx);
        const float corr = __expf(mrow[r] - mn);
        mrow[r] = mn;
        float psum = 0.0f;
#pragma unroll
        for (int nt = 0; nt < 4; ++nt) {
          const float p = __expf(sacc[nt][r] - mn);
          sacc[nt][r] = p;
          psum += p;
        }
#pragma unroll
        for (int off = 1; off < 16; off <<= 1) psum += __shfl_xor(psum, off);
        lrow[r] = lrow[r] * corr + psum;
#pragma unroll
        for (int nt = 0; nt < 4; ++nt) oacc[nt][r] *= corr;
#pragma unroll
        for (int nt = 0; nt < 4; ++nt)
          Ps[wave * 16 + quad * 4 + r][nt * 16 + m16] = f2bf(sacc[nt][r]);
      }
      bf16x8 pf0 = *reinterpret_cast<const bf16x8*>(&Ps[wave * 16 + m16][quad * 8]);
      bf16x8 pf1 = *reinterpret_cast<const bf16x8*>(&Ps[wave * 16 + m16][32 + quad * 8]);
#pragma unroll
      for (int nt = 0; nt < 4; ++nt) {
        bf16x8 vf0 = *reinterpret_cast<const bf16x8*>(&Vt[nt * 16 + m16][quad * 8]);
        bf16x8 vf1 = *reinterpret_cast<const bf16x8*>(&Vt[nt * 16 + m16][32 + quad * 8]);
        oacc[nt] = __builtin_amdgcn_mfma_f32_16x16x32_bf16(pf0, vf0, oacc[nt], 0, 0, 0);
        oacc[nt] = __builtin_amdgcn_mfma_f32_16x16x32_bf16(pf1, vf1, oacc[nt], 0, 0, 0);
      }
    }
    __syncthreads();
  }

  float inv[4];
#pragma unroll
  for (int r = 0; r < 4; ++r) inv[r] = 1.0f / lrow[r];
#pragma unroll
  for (int r = 0; r < 4; ++r) {
    bf16* op = Ob + (size_t)(b * Ssz + q0 + wave * 16 + quad * 4 + r) * Dm + h * 64 + m16;
#pragma unroll
    for (int nt = 0; nt < 4; ++nt) op[nt * 16] = f2bf(oacc[nt][r] * inv[r]);
  }
}

extern "C" void kernel_launch(void* const* d_in, const int* in_sizes, int n_in,
                              void* d_out, int out_size, void* d_ws, size_t ws_size,
                              hipStream_t stream) {
  char* ws = (char*)d_ws;
  int* flagp   = (int*)ws;                          // [0,1MB) control
  float* resid = (float*)(ws + (1ull << 20));       // 16MB fp32 residual
  bf16* xln    = (bf16*)(ws + (17ull << 20));       // 8MB LN output
  bf16* aout   = (bf16*)(ws + (25ull << 20));       // 8MB attn out
  bf16* big    = (bf16*)(ws + (33ull << 20));       // 32MB: qkv | qb | ffn1
  size_t off   = (65ull << 20);                     // canonical bf16 inputs

  detect_kernel<<<1, 64, 0, stream>>>((const unsigned*)d_in[3], flagp);

  CanonArgs ca;
  bf16* c[23];
  for (int i = 0; i < 23; ++i) {
    if (i == 2) { c[i] = nullptr; ca.src[i] = d_in[i]; ca.dst[i] = nullptr; ca.n[i] = 0; continue; }
    c[i] = (bf16*)(ws + off);
    const int n = in_sizes[i];
    off += ((size_t)n * 2 + 255) & ~(size_t)255;
    ca.src[i] = d_in[i];
    ca.dst[i] = c[i];
    ca.n[i] = n;
  }
  canon_all<<<dim3(256, 23), 256, 0, stream>>>(ca, resid, flagp);

  const bf16 *memory = c[1], *rope_cos = c[3], *rope_sin = c[4];
  const bf16 *qkv_w = c[5], *qkv_b = c[6], *out_w = c[7], *out_b = c[8];
  const bf16 *ca_in_w = c[9], *ca_in_b = c[10], *ca_out_w = c[11], *ca_out_b = c[12];
  const bf16 *ffn_w1 = c[13], *ffn_b1 = c[14], *ffn_w2 = c[15], *ffn_b2 = c[16];
  const bf16 *ln1_g = c[17], *ln1_b = c[18], *ln2_g = c[19], *ln2_b = c[20];
  const bf16 *ln3_g = c[21], *ln3_b = c[22];

  bf16* qb = big;
  bf16* kb = (bf16*)(ws + (41ull << 20));
  bf16* vb = (bf16*)(ws + (43ull << 20));
  bf16* outB = (bf16*)d_out;
  float* outF = (float*)d_out;

  const int ROWS = Bn * Ssz;   // 4096
  const float scale = 0.125f;  // 1/sqrt(64)

  // ---- self attention ----
  ln_kernel<<<ROWS, 256, 0, stream>>>(resid, ln1_g, ln1_b, xln);
  gemm128<<<dim3(ROWS / 128, (3 * Dm) / 128), 512, 0, stream>>>(
      xln, qkv_w, qkv_b, big, nullptr, nullptr, nullptr, nullptr, ROWS, 3 * Dm, Dm, 0);
  rope_kernel<<<(ROWS * Hh * (HDd / 2)) / 256, 256, 0, stream>>>(big, rope_cos, rope_sin);
  attn_mfma<<<dim3(Ssz / 128, Hh, Bn), 512, 0, stream>>>(
      big, big + Dm, big + 2 * Dm, aout, 3 * Dm, 3 * Dm, Ssz, 1, scale);
  gemm128<<<dim3(ROWS / 128, Dm / 128), 512, 0, stream>>>(
      aout, out_w, out_b, nullptr, nullptr, resid, resid, nullptr, ROWS, Dm, Dm, 2);

  // ---- cross attention ----
  ln_kernel<<<ROWS, 256, 0, stream>>>(resid, ln2_g, ln2_b, xln);
  gemm128<<<dim3(ROWS / 128, Dm / 128), 512, 0, stream>>>(
      xln, ca_in_w, ca_in_b, qb, nullptr, nullptr, nullptr, nullptr, ROWS, Dm, Dm, 0);
  gemm_bt<<<dim3((Bn * MEMn) / 64, Dm / 64), 256, 0, stream>>>(
      memory, ca_in_w + (size_t)Dm * Dm, ca_in_b + Dm, kb, nullptr, nullptr, nullptr, nullptr,
      Bn * MEMn, Dm, Dm, 0);
  gemm_bt<<<dim3((Bn * MEMn) / 64, Dm / 64), 256, 0, stream>>>(
      memory, ca_in_w + (size_t)2 * Dm * Dm, ca_in_b + 2 * Dm, vb, nullptr, nullptr, nullptr, nullptr,
      Bn * MEMn, Dm, Dm, 0);
  attn_mfma<<<dim3(Ssz / 128, Hh, Bn), 512, 0, stream>>>(
      qb, kb, vb, aout, Dm, Dm, MEMn, 0, scale);
  gemm128<<<dim3(ROWS / 128, Dm / 128), 512, 0, stream>>>(
      aout, ca_out_w, ca_out_b, nullptr, nullptr, resid, resid, nullptr, ROWS, Dm, Dm, 2);

  // ---- FFN ----
  ln_kernel<<<ROWS, 256, 0, stream>>>(resid, ln3_g, ln3_b, xln);
  gemm128<<<dim3(ROWS / 128, DFFn / 128), 512, 0, stream>>>(
      xln, ffn_w1, ffn_b1, big, nullptr, nullptr, nullptr, nullptr, ROWS, DFFn, Dm, 1);
  gemm128<<<dim3(ROWS / 128, Dm / 128), 512, 0, stream>>>(
      big, ffn_w2, ffn_b2, outB, outF, resid, nullptr, flagp, ROWS, Dm, DFFn, 3);
}

// Round 8
// 519.391 us; speedup vs baseline: 1.2649x; 1.0003x over previous
//
#include <hip/hip_runtime.h>
#include <hip/hip_bf16.h>

// PhraseDecoderLayer: B=4,S=1024,D=1024,H=16,HD=64,DFF=4096,MEM=256.
// Round 17: add gemm256 (256x256 tile, BK=64, 8 waves, wave-tile 128x64) for
// ffn1 + qkv (big-N GEMMs; ffn1 grid = 256 blocks = 1/CU exactly).
// Rationale: ffn1 on 8-wave gemm128 = 86.7us, MfmaUtil 16% -- per-CU-step
// budget is ~1540cy LDS-read of 3250cy (amplification (1/32+1/64)/MAC x 2
// blocks). 256^2/128x64 wave-tile halves LDS bytes per MAC; BK=64 gives
// 128B LDS rows so the XOR chunk swizzle (stage chunk (lane&7)^(lane>>3),
// read chunk (quad+4kk)^(m16&7)) balances all 32 banks (uniform 8 lanes per
// 4-bank slot = BW floor). Schedule = safe 2-phase counted pattern:
// vmcnt(0) -> barrier -> 24 ds_reads -> STAGE(t+1) -> 64 MFMA; 2x64KB bufs.
// N=1024 GEMMs + ffn2 stay on 512t gemm128; attn/gemm_bt/LN/canon unchanged.

using bf16 = __hip_bfloat16;
typedef __bf16 bf16x8 __attribute__((ext_vector_type(8)));
typedef float f32x4 __attribute__((ext_vector_type(4)));

static constexpr int Bn = 4, Ssz = 1024, Dm = 1024, Hh = 16, HDd = 64, DFFn = 4096, MEMn = 256;

__device__ inline float bf2f(bf16 x) { return __bfloat162float(x); }
__device__ inline bf16 f2bf(float x) { return __float2bfloat16(x); }

// async global->LDS, 16B per lane. LDS dest must be linear in tid (wave-uniform
// base + lane*16); caller guarantees &lds byte offset == tid*16 within segment.
__device__ __forceinline__ void gload16(const bf16* g, bf16* l) {
  __builtin_amdgcn_global_load_lds(
      (const __attribute__((address_space(1))) void*)g,
      (__attribute__((address_space(3))) void*)l, 16, 0, 0);
}

// ---------------- dtype detect ----------------
__global__ void detect_kernel(const unsigned* __restrict__ cosw, int* __restrict__ flag) {
  if (threadIdx.x == 0) *flag = (cosw[0] == 0x3F800000u) ? 1 : 0;
}

// ---------------- fused canonicalize: all inputs -> bf16 (+f32 resid for seg0) ----
struct CanonArgs {
  const void* src[23];
  void* dst[23];
  int n[23];  // element count (0 = skip); all counts divisible by 4
};
__global__ __launch_bounds__(256) void canon_all(CanonArgs a, float* __restrict__ resid,
                                                 const int* __restrict__ flagp) {
  const int seg = blockIdx.y;
  const int n4 = a.n[seg] >> 2;
  if (n4 == 0) return;
  const int fl = *flagp;  // wave-uniform
  if (fl) {
    const float4* s = (const float4*)a.src[seg];
    bf16* d = (bf16*)a.dst[seg];
    for (int i = blockIdx.x * 256 + threadIdx.x; i < n4; i += gridDim.x * 256) {
      float4 v = s[i];
      bf16 t[4] = {f2bf(v.x), f2bf(v.y), f2bf(v.z), f2bf(v.w)};
      *reinterpret_cast<unsigned long long*>(d + i * 4) =
          *reinterpret_cast<unsigned long long*>(t);
      if (seg == 0) *reinterpret_cast<float4*>(resid + i * 4) = v;
    }
  } else {
    const unsigned long long* s = (const unsigned long long*)a.src[seg];
    unsigned long long* d = (unsigned long long*)a.dst[seg];
    for (int i = blockIdx.x * 256 + threadIdx.x; i < n4; i += gridDim.x * 256) {
      unsigned long long v = s[i];
      d[i] = v;
      if (seg == 0) {
        const unsigned short* u = reinterpret_cast<const unsigned short*>(&v);
        float4 f;
        f.x = __uint_as_float(((unsigned)u[0]) << 16);
        f.y = __uint_as_float(((unsigned)u[1]) << 16);
        f.z = __uint_as_float(((unsigned)u[2]) << 16);
        f.w = __uint_as_float(((unsigned)u[3]) << 16);
        *reinterpret_cast<float4*>(resid + i * 4) = f;
      }
    }
  }
}

// ---------------- LayerNorm (rows of 1024, fp32 in, bf16 out) ----------------
__global__ __launch_bounds__(256) void ln_kernel(const float* __restrict__ x,
                                                 const bf16* __restrict__ g,
                                                 const bf16* __restrict__ bb,
                                                 bf16* __restrict__ y) {
  const int row = blockIdx.x;
  const float* xr = x + (size_t)row * Dm;
  const int i0 = threadIdx.x * 4;
  float4 v = *reinterpret_cast<const float4*>(xr + i0);
  float s = v.x + v.y + v.z + v.w;
  float ss = v.x * v.x + v.y * v.y + v.z * v.z + v.w * v.w;
#pragma unroll
  for (int o = 32; o > 0; o >>= 1) {
    s += __shfl_down(s, o);
    ss += __shfl_down(ss, o);
  }
  __shared__ float shs[4], shss[4];
  const int wave = threadIdx.x >> 6, lane = threadIdx.x & 63;
  if (lane == 0) { shs[wave] = s; shss[wave] = ss; }
  __syncthreads();
  s = shs[0] + shs[1] + shs[2] + shs[3];
  ss = shss[0] + shss[1] + shss[2] + shss[3];
  const float mu = s * (1.0f / Dm);
  const float var = fmaxf(ss * (1.0f / Dm) - mu * mu, 0.0f);
  const float rs = rsqrtf(var + 1e-5f);
  bf16* yr = y + (size_t)row * Dm + i0;
  float vv[4] = {v.x, v.y, v.z, v.w};
#pragma unroll
  for (int j = 0; j < 4; ++j)
    yr[j] = f2bf((vv[j] - mu) * rs * bf2f(g[i0 + j]) + bf2f(bb[i0 + j]));
}

// ---------------- GEMM 64x64 (round-2 verified; used for M=1024 kv) --------
__global__ __launch_bounds__(256) void gemm_bt(
    const bf16* __restrict__ A, const bf16* __restrict__ W,
    const bf16* __restrict__ bias, bf16* __restrict__ outB, float* __restrict__ outF,
    const float* __restrict__ residIn, float* __restrict__ residOut,
    const int* __restrict__ flagp, int M, int N, int K, int epi) {
  __shared__ bf16 As[64][40];
  __shared__ bf16 Ws[64][40];
  const int tid = threadIdx.x;
  const int m0 = blockIdx.x * 64, n0 = blockIdx.y * 64;
  const int wave = tid >> 6, lane = tid & 63;
  const int wm = wave >> 1, wn = wave & 1;
  const int quad = lane >> 4, m16 = lane & 15;
  const int lr = tid >> 2, lc = (tid & 3) * 8;

  f32x4 acc[2][2] = {};

  const bf16* Ap = A + (size_t)(m0 + lr) * K + lc;
  const bf16* Wp = W + (size_t)(n0 + lr) * K + lc;
  for (int k0 = 0; k0 < K; k0 += 32) {
    float4 av = *reinterpret_cast<const float4*>(Ap + k0);
    float4 wv = *reinterpret_cast<const float4*>(Wp + k0);
    *reinterpret_cast<float4*>(&As[lr][lc]) = av;
    *reinterpret_cast<float4*>(&Ws[lr][lc]) = wv;
    __syncthreads();
    bf16x8 aF[2], bF[2];
#pragma unroll
    for (int t = 0; t < 2; ++t) {
      aF[t] = *reinterpret_cast<const bf16x8*>(&As[wm * 32 + t * 16 + m16][quad * 8]);
      bF[t] = *reinterpret_cast<const bf16x8*>(&Ws[wn * 32 + t * 16 + m16][quad * 8]);
    }
#pragma unroll
    for (int mt = 0; mt < 2; ++mt)
#pragma unroll
      for (int nt = 0; nt < 2; ++nt)
        acc[mt][nt] = __builtin_amdgcn_mfma_f32_16x16x32_bf16(aF[mt], bF[nt], acc[mt][nt], 0, 0, 0);
    __syncthreads();
  }
  const int fl = (epi == 3) ? *flagp : 0;
#pragma unroll
  for (int mt = 0; mt < 2; ++mt) {
#pragma unroll
    for (int nt = 0; nt < 2; ++nt) {
      const int col = n0 + wn * 32 + nt * 16 + m16;
      const float bv = bf2f(bias[col]);
#pragma unroll
      for (int r = 0; r < 4; ++r) {
        const int row = m0 + wm * 32 + mt * 16 + quad * 4 + r;
        const size_t idx = (size_t)row * N + col;
        float v = acc[mt][nt][r] + bv;
        if (epi == 0) {
          outB[idx] = f2bf(v);
        } else if (epi == 1) {
          outB[idx] = f2bf(0.5f * v * (1.0f + erff(v * 0.70710678118654752f)));
        } else if (epi == 2) {
          residOut[idx] = residIn[idx] + v;
        } else {
          const float rr = residIn[idx] + v;
          if (fl) outF[idx] = rr; else outB[idx] = f2bf(rr);
        }
      }
    }
  }
}

// ---------------- GEMM 128x128: 8-wave depth-3 counted-vmcnt DMA pipeline ---
// (round-14 verified) Used for N=1024 GEMMs (out/ca_q/ca_out/ffn2).
__global__ __launch_bounds__(512) void gemm128(
    const bf16* __restrict__ A, const bf16* __restrict__ W,
    const bf16* __restrict__ bias, bf16* __restrict__ outB, float* __restrict__ outF,
    const float* __restrict__ residIn, float* __restrict__ residOut,
    const int* __restrict__ flagp, int M, int N, int K, int epi) {
  __shared__ bf16 As[4][128][32];
  __shared__ bf16 Ws[4][128][32];
  const int tid = threadIdx.x;
  const int wave = tid >> 6, lane = tid & 63;
  const int wm = wave >> 1;      // 0..3 (32-row group)
  const int wn = wave & 1;       // 0..1 (64-col group)
  const int quad = lane >> 4, m16 = lane & 15;
  const int m0 = blockIdx.x * 128, n0 = blockIdx.y * 128;

  const int sr = tid >> 2;       // 0..127 (tile row)
  const int sc = (tid & 3) * 8;  // 0,8,16,24 (k-col)
  const bf16* Ap = A + (size_t)(m0 + sr) * K + sc;
  const bf16* Wp = W + (size_t)(n0 + sr) * K + sc;

  f32x4 acc[2][4] = {};

#define STAGE128(T, BUF)                                   \
  {                                                        \
    const int kk_ = (T) * 32;                              \
    gload16(Ap + kk_, &As[BUF][sr][sc]);                   \
    gload16(Wp + kk_, &Ws[BUF][sr][sc]);                   \
  }

#define READS128(RB)                                                                        \
  _Pragma("unroll") for (int tt = 0; tt < 2; ++tt)                                          \
    aF[tt] = *reinterpret_cast<const bf16x8*>(&As[RB][wm * 32 + tt * 16 + m16][quad * 8]);  \
  _Pragma("unroll") for (int nt = 0; nt < 4; ++nt)                                          \
    bF[nt] = *reinterpret_cast<const bf16x8*>(&Ws[RB][wn * 64 + nt * 16 + m16][quad * 8]);

#define MFMAS128                                                                            \
  _Pragma("unroll") for (int mt = 0; mt < 2; ++mt)                                          \
  _Pragma("unroll") for (int nt = 0; nt < 4; ++nt)                                          \
    acc[mt][nt] = __builtin_amdgcn_mfma_f32_16x16x32_bf16(aF[mt], bF[nt], acc[mt][nt], 0, 0, 0);

  const int nsteps = K >> 5;  // K=1024 or 4096 -> 32 or 128 steps
  STAGE128(0, 0)
  STAGE128(1, 1)
  STAGE128(2, 2)

  int rb = 0, sb = 3;
  for (int t = 0; t < nsteps - 2; ++t) {
    asm volatile("s_waitcnt vmcnt(4)" ::: "memory");
    __builtin_amdgcn_s_barrier();
    __builtin_amdgcn_sched_barrier(0);
    bf16x8 aF[2], bF[4];
    READS128(rb)
    __builtin_amdgcn_sched_barrier(0);
    if (t + 3 < nsteps) { STAGE128(t + 3, sb) }
    __builtin_amdgcn_sched_barrier(0);
    MFMAS128
    rb = (rb + 1 == 4) ? 0 : rb + 1;
    sb = (sb + 1 == 4) ? 0 : sb + 1;
  }
  {  // t = nsteps-2: outstanding tiles {t, t+1} = 4 loads -> wait 2 = tile t
    asm volatile("s_waitcnt vmcnt(2)" ::: "memory");
    __builtin_amdgcn_s_barrier();
    __builtin_amdgcn_sched_barrier(0);
    bf16x8 aF[2], bF[4];
    READS128(rb)
    MFMAS128
    rb = (rb + 1 == 4) ? 0 : rb + 1;
  }
  {  // t = nsteps-1
    asm volatile("s_waitcnt vmcnt(0)" ::: "memory");
    __builtin_amdgcn_s_barrier();
    __builtin_amdgcn_sched_barrier(0);
    bf16x8 aF[2], bF[4];
    READS128(rb)
    MFMAS128
  }
#undef STAGE128
#undef READS128
#undef MFMAS128

  const int fl = (epi == 3) ? *flagp : 0;
  // C/D layout: col = lane&15, row = quad*4 + reg
#pragma unroll
  for (int mt = 0; mt < 2; ++mt) {
#pragma unroll
    for (int nt = 0; nt < 4; ++nt) {
      const int col = n0 + wn * 64 + nt * 16 + m16;
      const float bv = bf2f(bias[col]);
#pragma unroll
      for (int r = 0; r < 4; ++r) {
        const int row = m0 + wm * 32 + mt * 16 + quad * 4 + r;
        const size_t idx = (size_t)row * N + col;
        float v = acc[mt][nt][r] + bv;
        if (epi == 0) {
          outB[idx] = f2bf(v);
        } else if (epi == 1) {
          outB[idx] = f2bf(0.5f * v * (1.0f + erff(v * 0.70710678118654752f)));
        } else if (epi == 2) {
          residOut[idx] = residIn[idx] + v;
        } else {
          const float rr = residIn[idx] + v;
          if (fl) outF[idx] = rr; else outB[idx] = f2bf(rr);
        }
      }
    }
  }
}

// ---------------- GEMM 256x256 (BK=64, swizzled LDS) for big-N GEMMs -------
// 8 waves, wave-tile 128x64 (wm=wave>>2, wn=wave&3), acc[8][4].
// LDS: 2 x (A 32KB + B 32KB) = 128KB. 128B rows (64 bf16) -> XOR chunk
// swizzle balances banks: stage global chunk = (lane&7)^(lane>>3), read
// phys chunk = (quad+4kk)^(m16&7). Both sides use the same involution
// (rule 21); DMA dest stays linear (base + lane*16 per instruction).
// Schedule (2-phase counted, m248): vmcnt(0) -> barrier -> 24 ds_reads ->
// STAGE(t+1 -> other buf) -> 64 MFMA. Safe: stage target was last read in
// step t-1, whose reads completed before barrier t; vmcnt(0)+barrier makes
// all waves' stage(t) visible before any read.
__global__ __launch_bounds__(512) void gemm256(
    const bf16* __restrict__ A, const bf16* __restrict__ W,
    const bf16* __restrict__ bias, bf16* __restrict__ outB,
    int M, int N, int K, int epi) {
  __shared__ bf16 Abuf[2][256 * 64];
  __shared__ bf16 Bbuf[2][256 * 64];
  const int tid = threadIdx.x;
  const int wave = tid >> 6, lane = tid & 63;
  const int wm = wave >> 2, wn = wave & 3;
  const int quad = lane >> 4, m16 = lane & 15;
  const int m0 = blockIdx.x * 256, n0 = blockIdx.y * 256;
  const int lr8 = lane >> 3, lc8 = lane & 7;
  const int gch = (lc8 ^ lr8) * 8;  // stage-side swizzled k-chunk (elements)
  const int swz = m16 & 7;          // read-side row swizzle key

  f32x4 acc[8][4] = {};

#define STAGE256(T, BUF)                                                         \
  { const int kb_ = (T) * 64 + gch;                                              \
    _Pragma("unroll") for (int i = 0; i < 4; ++i) {                              \
      const int rr = (wave * 4 + i) * 8 + lr8;                                   \
      gload16(A + (size_t)(m0 + rr) * K + kb_, &Abuf[BUF][rr * 64 + lc8 * 8]);   \
      gload16(W + (size_t)(n0 + rr) * K + kb_, &Bbuf[BUF][rr * 64 + lc8 * 8]);   \
    } }

  const int nsteps = K >> 6;  // K=1024 -> 16 steps
  STAGE256(0, 0)
  for (int t = 0; t < nsteps; ++t) {
    asm volatile("s_waitcnt vmcnt(0)" ::: "memory");
    __builtin_amdgcn_s_barrier();
    __builtin_amdgcn_sched_barrier(0);
    const int rb = t & 1;
    bf16x8 aF[2][8], bF[2][4];
#pragma unroll
    for (int kk = 0; kk < 2; ++kk) {
      const int cswz = ((quad + 4 * kk) ^ swz) * 8;
#pragma unroll
      for (int tt = 0; tt < 8; ++tt)
        aF[kk][tt] = *reinterpret_cast<const bf16x8*>(
            &Abuf[rb][(wm * 128 + tt * 16 + m16) * 64 + cswz]);
#pragma unroll
      for (int nt = 0; nt < 4; ++nt)
        bF[kk][nt] = *reinterpret_cast<const bf16x8*>(
            &Bbuf[rb][(wn * 64 + nt * 16 + m16) * 64 + cswz]);
    }
    __builtin_amdgcn_sched_barrier(0);
    if (t + 1 < nsteps) { STAGE256(t + 1, rb ^ 1) }
    __builtin_amdgcn_sched_barrier(0);
#pragma unroll
    for (int kk = 0; kk < 2; ++kk)
#pragma unroll
      for (int mt = 0; mt < 8; ++mt)
#pragma unroll
        for (int nt = 0; nt < 4; ++nt)
          acc[mt][nt] = __builtin_amdgcn_mfma_f32_16x16x32_bf16(
              aF[kk][mt], bF[kk][nt], acc[mt][nt], 0, 0, 0);
  }
#undef STAGE256

  // C/D layout: col = lane&15, row = quad*4 + reg
#pragma unroll
  for (int mt = 0; mt < 8; ++mt) {
#pragma unroll
    for (int nt = 0; nt < 4; ++nt) {
      const int col = n0 + wn * 64 + nt * 16 + m16;
      const float bv = bf2f(bias[col]);
#pragma unroll
      for (int r = 0; r < 4; ++r) {
        const int row = m0 + wm * 128 + mt * 16 + quad * 4 + r;
        const size_t idx = (size_t)row * N + col;
        float v = acc[mt][nt][r] + bv;
        outB[idx] = (epi == 1)
                        ? f2bf(0.5f * v * (1.0f + erff(v * 0.70710678118654752f)))
                        : f2bf(v);
      }
    }
  }
}

// ---------------- RoPE in-place on qkv buffer [4096, 3072] ----------------
__global__ __launch_bounds__(256) void rope_kernel(bf16* __restrict__ qkv,
                                                   const bf16* __restrict__ cosb,
                                                   const bf16* __restrict__ sinb) {
  const int idx = blockIdx.x * 256 + threadIdx.x;  // over 4096*16*32
  const int i = idx & 31;
  const int h = (idx >> 5) & 15;
  const int r = idx >> 9;
  const int s = r & (Ssz - 1);
  const float c = bf2f(cosb[s * 32 + i]);
  const float sn = bf2f(sinb[s * 32 + i]);
  bf16* base = qkv + (size_t)r * (3 * Dm) + h * 64 + 2 * i;
  float x0 = bf2f(base[0]), x1 = bf2f(base[1]);
  base[0] = f2bf(x0 * c - x1 * sn);
  base[1] = f2bf(x0 * sn + x1 * c);
  x0 = bf2f(base[Dm]); x1 = bf2f(base[Dm + 1]);
  base[Dm] = f2bf(x0 * c - x1 * sn);
  base[Dm + 1] = f2bf(x0 * sn + x1 * c);
}

// ---------------- MFMA flash attention: 8 waves, 128-row Q tile ----------------
__global__ __launch_bounds__(512) void attn_mfma(
    const bf16* __restrict__ Qb, const bf16* __restrict__ Kb, const bf16* __restrict__ Vb,
    bf16* __restrict__ Ob, int qStride, int kvStride, int kvLen, int causal, float scale) {
  __shared__ bf16 Ks[64][72];
  __shared__ bf16 Vt[64][72];
  __shared__ bf16 Ps[128][72];
  const int tid = threadIdx.x;
  const int wave = tid >> 6, lane = tid & 63;
  const int quad = lane >> 4, m16 = lane & 15;
  const int b = blockIdx.z, h = blockIdx.y;
  const int q0 = blockIdx.x * 128;

  {  // Q staging: 512 thr x 32B = 16KB
    const int sr = tid >> 2, sc = (tid & 3) * 16;
    const bf16* qp = Qb + (size_t)(b * Ssz + q0 + sr) * qStride + h * 64 + sc;
    float4 a = reinterpret_cast<const float4*>(qp)[0];
    float4 bb2 = reinterpret_cast<const float4*>(qp)[1];
    *reinterpret_cast<float4*>(&Ps[sr][sc]) = a;
    *reinterpret_cast<float4*>(&Ps[sr][sc + 8]) = bb2;
  }
  __syncthreads();
  bf16x8 qf[2];
  qf[0] = *reinterpret_cast<const bf16x8*>(&Ps[wave * 16 + m16][quad * 8]);
  qf[1] = *reinterpret_cast<const bf16x8*>(&Ps[wave * 16 + m16][32 + quad * 8]);

  f32x4 oacc[4] = {};
  float mrow[4], lrow[4];
#pragma unroll
  for (int r = 0; r < 4; ++r) { mrow[r] = -30000.0f; lrow[r] = 0.0f; }

  const int wrow0 = q0 + wave * 16;  // this wave's first q row
  const int nk = causal ? (q0 + 128) : kvLen;
  for (int kt = 0; kt < nk; kt += 64) {
    {  // K/V staging: row = lane, d-block = 8*wave
      const int dbase = wave * 8;
      const bf16* kp = Kb + (size_t)(b * kvLen + kt + lane) * kvStride + h * 64 + dbase;
      float4 k1 = *reinterpret_cast<const float4*>(kp);
      *reinterpret_cast<float4*>(&Ks[lane][dbase]) = k1;
      const bf16* vp = Vb + (size_t)(b * kvLen + kt + lane) * kvStride + h * 64 + dbase;
      float4 v1 = *reinterpret_cast<const float4*>(vp);
      const bf16* tv = reinterpret_cast<const bf16*>(&v1);
#pragma unroll
      for (int j = 0; j < 8; ++j) Vt[dbase + j][lane] = tv[j];
    }
    __syncthreads();

    const bool live = (causal == 0) || (kt <= wrow0 + 15);
    if (live) {
      f32x4 sacc[4] = {};
#pragma unroll
      for (int nt = 0; nt < 4; ++nt) {
        bf16x8 kf0 = *reinterpret_cast<const bf16x8*>(&Ks[nt * 16 + m16][quad * 8]);
        bf16x8 kf1 = *reinterpret_cast<const bf16x8*>(&Ks[nt * 16 + m16][32 + quad * 8]);
        sacc[nt] = __builtin_amdgcn_mfma_f32_16x16x32_bf16(qf[0], kf0, sacc[nt], 0, 0, 0);
        sacc[nt] = __builtin_amdgcn_mfma_f32_16x16x32_bf16(qf[1], kf1, sacc[nt], 0, 0, 0);
      }
      const bool dmask = (causal != 0) && (kt + 63 > wrow0);
#pragma unroll
      for (int nt = 0; nt < 4; ++nt) {
#pragma unroll
        for (int r = 0; r < 4; ++r) {
          float s = sacc[nt][r] * scale;
          if (dmask && (kt + nt * 16 + m16 > wrow0 + quad * 4 + r)) s = -30000.0f;
          sacc[nt][r] = s;
        }
      }

#pragma unroll
      for (int r = 0; r < 4; ++r) {
        float mx = fmaxf(fmaxf(sacc[0][r], sacc[1][r]), fmaxf(sacc[2][r], sacc[3][r]));
#pragma unroll
        for (int off = 1; off < 16; off <<= 1) mx = fmaxf(mx, __shfl_xor(mx, off));
        const float mn = fmaxf(mrow[r], mx);
        const float corr = __expf(mrow[r] - mn);
        mrow[r] = mn;
        float psum = 0.0f;
#pragma unroll
        for (int nt = 0; nt < 4; ++nt) {
          const float p = __expf(sacc[nt][r] - mn);
          sacc[nt][r] = p;
          psum += p;
        }
#pragma unroll
        for (int off = 1; off < 16; off <<= 1) psum += __shfl_xor(psum, off);
        lrow[r] = lrow[r] * corr + psum;
#pragma unroll
        for (int nt = 0; nt < 4; ++nt) oacc[nt][r] *= corr;
#pragma unroll
        for (int nt = 0; nt < 4; ++nt)
          Ps[wave * 16 + quad * 4 + r][nt * 16 + m16] = f2bf(sacc[nt][r]);
      }
      bf16x8 pf0 = *reinterpret_cast<const bf16x8*>(&Ps[wave * 16 + m16][quad * 8]);
      bf16x8 pf1 = *reinterpret_cast<const bf16x8*>(&Ps[wave * 16 + m16][32 + quad * 8]);
#pragma unroll
      for (int nt = 0; nt < 4; ++nt) {
        bf16x8 vf0 = *reinterpret_cast<const bf16x8*>(&Vt[nt * 16 + m16][quad * 8]);
        bf16x8 vf1 = *reinterpret_cast<const bf16x8*>(&Vt[nt * 16 + m16][32 + quad * 8]);
        oacc[nt] = __builtin_amdgcn_mfma_f32_16x16x32_bf16(pf0, vf0, oacc[nt], 0, 0, 0);
        oacc[nt] = __builtin_amdgcn_mfma_f32_16x16x32_bf16(pf1, vf1, oacc[nt], 0, 0, 0);
      }
    }
    __syncthreads();
  }

  float inv[4];
#pragma unroll
  for (int r = 0; r < 4; ++r) inv[r] = 1.0f / lrow[r];
#pragma unroll
  for (int r = 0; r < 4; ++r) {
    bf16* op = Ob + (size_t)(b * Ssz + q0 + wave * 16 + quad * 4 + r) * Dm + h * 64 + m16;
#pragma unroll
    for (int nt = 0; nt < 4; ++nt) op[nt * 16] = f2bf(oacc[nt][r] * inv[r]);
  }
}

extern "C" void kernel_launch(void* const* d_in, const int* in_sizes, int n_in,
                              void* d_out, int out_size, void* d_ws, size_t ws_size,
                              hipStream_t stream) {
  char* ws = (char*)d_ws;
  int* flagp   = (int*)ws;                          // [0,1MB) control
  float* resid = (float*)(ws + (1ull << 20));       // 16MB fp32 residual
  bf16* xln    = (bf16*)(ws + (17ull << 20));       // 8MB LN output
  bf16* aout   = (bf16*)(ws + (25ull << 20));       // 8MB attn out
  bf16* big    = (bf16*)(ws + (33ull << 20));       // 32MB: qkv | qb | ffn1
  size_t off   = (65ull << 20);                     // canonical bf16 inputs

  detect_kernel<<<1, 64, 0, stream>>>((const unsigned*)d_in[3], flagp);

  CanonArgs ca;
  bf16* c[23];
  for (int i = 0; i < 23; ++i) {
    if (i == 2) { c[i] = nullptr; ca.src[i] = d_in[i]; ca.dst[i] = nullptr; ca.n[i] = 0; continue; }
    c[i] = (bf16*)(ws + off);
    const int n = in_sizes[i];
    off += ((size_t)n * 2 + 255) & ~(size_t)255;
    ca.src[i] = d_in[i];
    ca.dst[i] = c[i];
    ca.n[i] = n;
  }
  canon_all<<<dim3(256, 23), 256, 0, stream>>>(ca, resid, flagp);

  const bf16 *memory = c[1], *rope_cos = c[3], *rope_sin = c[4];
  const bf16 *qkv_w = c[5], *qkv_b = c[6], *out_w = c[7], *out_b = c[8];
  const bf16 *ca_in_w = c[9], *ca_in_b = c[10], *ca_out_w = c[11], *ca_out_b = c[12];
  const bf16 *ffn_w1 = c[13], *ffn_b1 = c[14], *ffn_w2 = c[15], *ffn_b2 = c[16];
  const bf16 *ln1_g = c[17], *ln1_b = c[18], *ln2_g = c[19], *ln2_b = c[20];
  const bf16 *ln3_g = c[21], *ln3_b = c[22];

  bf16* qb = big;
  bf16* kb = (bf16*)(ws + (41ull << 20));
  bf16* vb = (bf16*)(ws + (43ull << 20));
  bf16* outB = (bf16*)d_out;
  float* outF = (float*)d_out;

  const int ROWS = Bn * Ssz;   // 4096
  const float scale = 0.125f;  // 1/sqrt(64)

  // ---- self attention ----
  ln_kernel<<<ROWS, 256, 0, stream>>>(resid, ln1_g, ln1_b, xln);
  gemm256<<<dim3(ROWS / 256, (3 * Dm) / 256), 512, 0, stream>>>(
      xln, qkv_w, qkv_b, big, ROWS, 3 * Dm, Dm, 0);
  rope_kernel<<<(ROWS * Hh * (HDd / 2)) / 256, 256, 0, stream>>>(big, rope_cos, rope_sin);
  attn_mfma<<<dim3(Ssz / 128, Hh, Bn), 512, 0, stream>>>(
      big, big + Dm, big + 2 * Dm, aout, 3 * Dm, 3 * Dm, Ssz, 1, scale);
  gemm128<<<dim3(ROWS / 128, Dm / 128), 512, 0, stream>>>(
      aout, out_w, out_b, nullptr, nullptr, resid, resid, nullptr, ROWS, Dm, Dm, 2);

  // ---- cross attention ----
  ln_kernel<<<ROWS, 256, 0, stream>>>(resid, ln2_g, ln2_b, xln);
  gemm128<<<dim3(ROWS / 128, Dm / 128), 512, 0, stream>>>(
      xln, ca_in_w, ca_in_b, qb, nullptr, nullptr, nullptr, nullptr, ROWS, Dm, Dm, 0);
  gemm_bt<<<dim3((Bn * MEMn) / 64, Dm / 64), 256, 0, stream>>>(
      memory, ca_in_w + (size_t)Dm * Dm, ca_in_b + Dm, kb, nullptr, nullptr, nullptr, nullptr,
      Bn * MEMn, Dm, Dm, 0);
  gemm_bt<<<dim3((Bn * MEMn) / 64, Dm / 64), 256, 0, stream>>>(
      memory, ca_in_w + (size_t)2 * Dm * Dm, ca_in_b + 2 * Dm, vb, nullptr, nullptr, nullptr, nullptr,
      Bn * MEMn, Dm, Dm, 0);
  attn_mfma<<<dim3(Ssz / 128, Hh, Bn), 512, 0, stream>>>(
      qb, kb, vb, aout, Dm, Dm, MEMn, 0, scale);
  gemm128<<<dim3(ROWS / 128, Dm / 128), 512, 0, stream>>>(
      aout, ca_out_w, ca_out_b, nullptr, nullptr, resid, resid, nullptr, ROWS, Dm, Dm, 2);

  // ---- FFN ----
  ln_kernel<<<ROWS, 256, 0, stream>>>(resid, ln3_g, ln3_b, xln);
  gemm256<<<dim3(ROWS / 256, DFFn / 256), 512, 0, stream>>>(
      xln, ffn_w1, ffn_b1, big, ROWS, DFFn, Dm, 1);
  gemm128<<<dim3(ROWS / 128, Dm / 128), 512, 0, stream>>>(
      big, ffn_w2, ffn_b2, outB, outF, resid, nullptr, flagp, ROWS, Dm, DFFn, 3);
}

// Round 9
// 507.165 us; speedup vs baseline: 1.2954x; 1.0241x over previous
//
#include <hip/hip_runtime.h>
#include <hip/hip_bf16.h>

// PhraseDecoderLayer: B=4,S=1024,D=1024,H=16,HD=64,DFF=4096,MEM=256.
// Round 18: attn_mfma -> complementary q-tile pairing for causal balance.
// Round-17 post-mortem: self-attn 73.3us with Occupancy 19.7% (nominal 50%)
// -- causal imbalance: q-tile x does 2x+2 kv-tiles (2..16), and blocks c,
// c+256 (same x, since 256%8==0) land on the same CU -> pair sums 4..32.
// Fix: grid x = S/256 = 4; each block runs q-tiles {x, 7-x} sequentially ->
// 18 kv-tiles per block, every block equal, 256 blocks = 1/CU, no tail.
// Inner tile math unchanged (round-15 verified). Cross-attn same kernel
// (uniform 4+4 tiles). gemm256/gemm128/gemm_bt/LN/canon unchanged.

using bf16 = __hip_bfloat16;
typedef __bf16 bf16x8 __attribute__((ext_vector_type(8)));
typedef float f32x4 __attribute__((ext_vector_type(4)));

static constexpr int Bn = 4, Ssz = 1024, Dm = 1024, Hh = 16, HDd = 64, DFFn = 4096, MEMn = 256;

__device__ inline float bf2f(bf16 x) { return __bfloat162float(x); }
__device__ inline bf16 f2bf(float x) { return __float2bfloat16(x); }

// async global->LDS, 16B per lane. LDS dest must be linear in tid (wave-uniform
// base + lane*16); caller guarantees &lds byte offset == tid*16 within segment.
__device__ __forceinline__ void gload16(const bf16* g, bf16* l) {
  __builtin_amdgcn_global_load_lds(
      (const __attribute__((address_space(1))) void*)g,
      (__attribute__((address_space(3))) void*)l, 16, 0, 0);
}

// ---------------- dtype detect ----------------
__global__ void detect_kernel(const unsigned* __restrict__ cosw, int* __restrict__ flag) {
  if (threadIdx.x == 0) *flag = (cosw[0] == 0x3F800000u) ? 1 : 0;
}

// ---------------- fused canonicalize: all inputs -> bf16 (+f32 resid for seg0) ----
struct CanonArgs {
  const void* src[23];
  void* dst[23];
  int n[23];  // element count (0 = skip); all counts divisible by 4
};
__global__ __launch_bounds__(256) void canon_all(CanonArgs a, float* __restrict__ resid,
                                                 const int* __restrict__ flagp) {
  const int seg = blockIdx.y;
  const int n4 = a.n[seg] >> 2;
  if (n4 == 0) return;
  const int fl = *flagp;  // wave-uniform
  if (fl) {
    const float4* s = (const float4*)a.src[seg];
    bf16* d = (bf16*)a.dst[seg];
    for (int i = blockIdx.x * 256 + threadIdx.x; i < n4; i += gridDim.x * 256) {
      float4 v = s[i];
      bf16 t[4] = {f2bf(v.x), f2bf(v.y), f2bf(v.z), f2bf(v.w)};
      *reinterpret_cast<unsigned long long*>(d + i * 4) =
          *reinterpret_cast<unsigned long long*>(t);
      if (seg == 0) *reinterpret_cast<float4*>(resid + i * 4) = v;
    }
  } else {
    const unsigned long long* s = (const unsigned long long*)a.src[seg];
    unsigned long long* d = (unsigned long long*)a.dst[seg];
    for (int i = blockIdx.x * 256 + threadIdx.x; i < n4; i += gridDim.x * 256) {
      unsigned long long v = s[i];
      d[i] = v;
      if (seg == 0) {
        const unsigned short* u = reinterpret_cast<const unsigned short*>(&v);
        float4 f;
        f.x = __uint_as_float(((unsigned)u[0]) << 16);
        f.y = __uint_as_float(((unsigned)u[1]) << 16);
        f.z = __uint_as_float(((unsigned)u[2]) << 16);
        f.w = __uint_as_float(((unsigned)u[3]) << 16);
        *reinterpret_cast<float4*>(resid + i * 4) = f;
      }
    }
  }
}

// ---------------- LayerNorm (rows of 1024, fp32 in, bf16 out) ----------------
__global__ __launch_bounds__(256) void ln_kernel(const float* __restrict__ x,
                                                 const bf16* __restrict__ g,
                                                 const bf16* __restrict__ bb,
                                                 bf16* __restrict__ y) {
  const int row = blockIdx.x;
  const float* xr = x + (size_t)row * Dm;
  const int i0 = threadIdx.x * 4;
  float4 v = *reinterpret_cast<const float4*>(xr + i0);
  float s = v.x + v.y + v.z + v.w;
  float ss = v.x * v.x + v.y * v.y + v.z * v.z + v.w * v.w;
#pragma unroll
  for (int o = 32; o > 0; o >>= 1) {
    s += __shfl_down(s, o);
    ss += __shfl_down(ss, o);
  }
  __shared__ float shs[4], shss[4];
  const int wave = threadIdx.x >> 6, lane = threadIdx.x & 63;
  if (lane == 0) { shs[wave] = s; shss[wave] = ss; }
  __syncthreads();
  s = shs[0] + shs[1] + shs[2] + shs[3];
  ss = shss[0] + shss[1] + shss[2] + shss[3];
  const float mu = s * (1.0f / Dm);
  const float var = fmaxf(ss * (1.0f / Dm) - mu * mu, 0.0f);
  const float rs = rsqrtf(var + 1e-5f);
  bf16* yr = y + (size_t)row * Dm + i0;
  float vv[4] = {v.x, v.y, v.z, v.w};
#pragma unroll
  for (int j = 0; j < 4; ++j)
    yr[j] = f2bf((vv[j] - mu) * rs * bf2f(g[i0 + j]) + bf2f(bb[i0 + j]));
}

// ---------------- GEMM 64x64 (round-2 verified; used for M=1024 kv) --------
__global__ __launch_bounds__(256) void gemm_bt(
    const bf16* __restrict__ A, const bf16* __restrict__ W,
    const bf16* __restrict__ bias, bf16* __restrict__ outB, float* __restrict__ outF,
    const float* __restrict__ residIn, float* __restrict__ residOut,
    const int* __restrict__ flagp, int M, int N, int K, int epi) {
  __shared__ bf16 As[64][40];
  __shared__ bf16 Ws[64][40];
  const int tid = threadIdx.x;
  const int m0 = blockIdx.x * 64, n0 = blockIdx.y * 64;
  const int wave = tid >> 6, lane = tid & 63;
  const int wm = wave >> 1, wn = wave & 1;
  const int quad = lane >> 4, m16 = lane & 15;
  const int lr = tid >> 2, lc = (tid & 3) * 8;

  f32x4 acc[2][2] = {};

  const bf16* Ap = A + (size_t)(m0 + lr) * K + lc;
  const bf16* Wp = W + (size_t)(n0 + lr) * K + lc;
  for (int k0 = 0; k0 < K; k0 += 32) {
    float4 av = *reinterpret_cast<const float4*>(Ap + k0);
    float4 wv = *reinterpret_cast<const float4*>(Wp + k0);
    *reinterpret_cast<float4*>(&As[lr][lc]) = av;
    *reinterpret_cast<float4*>(&Ws[lr][lc]) = wv;
    __syncthreads();
    bf16x8 aF[2], bF[2];
#pragma unroll
    for (int t = 0; t < 2; ++t) {
      aF[t] = *reinterpret_cast<const bf16x8*>(&As[wm * 32 + t * 16 + m16][quad * 8]);
      bF[t] = *reinterpret_cast<const bf16x8*>(&Ws[wn * 32 + t * 16 + m16][quad * 8]);
    }
#pragma unroll
    for (int mt = 0; mt < 2; ++mt)
#pragma unroll
      for (int nt = 0; nt < 2; ++nt)
        acc[mt][nt] = __builtin_amdgcn_mfma_f32_16x16x32_bf16(aF[mt], bF[nt], acc[mt][nt], 0, 0, 0);
    __syncthreads();
  }
  const int fl = (epi == 3) ? *flagp : 0;
#pragma unroll
  for (int mt = 0; mt < 2; ++mt) {
#pragma unroll
    for (int nt = 0; nt < 2; ++nt) {
      const int col = n0 + wn * 32 + nt * 16 + m16;
      const float bv = bf2f(bias[col]);
#pragma unroll
      for (int r = 0; r < 4; ++r) {
        const int row = m0 + wm * 32 + mt * 16 + quad * 4 + r;
        const size_t idx = (size_t)row * N + col;
        float v = acc[mt][nt][r] + bv;
        if (epi == 0) {
          outB[idx] = f2bf(v);
        } else if (epi == 1) {
          outB[idx] = f2bf(0.5f * v * (1.0f + erff(v * 0.70710678118654752f)));
        } else if (epi == 2) {
          residOut[idx] = residIn[idx] + v;
        } else {
          const float rr = residIn[idx] + v;
          if (fl) outF[idx] = rr; else outB[idx] = f2bf(rr);
        }
      }
    }
  }
}

// ---------------- GEMM 128x128: 8-wave depth-3 counted-vmcnt DMA pipeline ---
// (round-14 verified) Used for N=1024 GEMMs (out/ca_q/ca_out/ffn2).
__global__ __launch_bounds__(512) void gemm128(
    const bf16* __restrict__ A, const bf16* __restrict__ W,
    const bf16* __restrict__ bias, bf16* __restrict__ outB, float* __restrict__ outF,
    const float* __restrict__ residIn, float* __restrict__ residOut,
    const int* __restrict__ flagp, int M, int N, int K, int epi) {
  __shared__ bf16 As[4][128][32];
  __shared__ bf16 Ws[4][128][32];
  const int tid = threadIdx.x;
  const int wave = tid >> 6, lane = tid & 63;
  const int wm = wave >> 1;      // 0..3 (32-row group)
  const int wn = wave & 1;       // 0..1 (64-col group)
  const int quad = lane >> 4, m16 = lane & 15;
  const int m0 = blockIdx.x * 128, n0 = blockIdx.y * 128;

  const int sr = tid >> 2;       // 0..127 (tile row)
  const int sc = (tid & 3) * 8;  // 0,8,16,24 (k-col)
  const bf16* Ap = A + (size_t)(m0 + sr) * K + sc;
  const bf16* Wp = W + (size_t)(n0 + sr) * K + sc;

  f32x4 acc[2][4] = {};

#define STAGE128(T, BUF)                                   \
  {                                                        \
    const int kk_ = (T) * 32;                              \
    gload16(Ap + kk_, &As[BUF][sr][sc]);                   \
    gload16(Wp + kk_, &Ws[BUF][sr][sc]);                   \
  }

#define READS128(RB)                                                                        \
  _Pragma("unroll") for (int tt = 0; tt < 2; ++tt)                                          \
    aF[tt] = *reinterpret_cast<const bf16x8*>(&As[RB][wm * 32 + tt * 16 + m16][quad * 8]);  \
  _Pragma("unroll") for (int nt = 0; nt < 4; ++nt)                                          \
    bF[nt] = *reinterpret_cast<const bf16x8*>(&Ws[RB][wn * 64 + nt * 16 + m16][quad * 8]);

#define MFMAS128                                                                            \
  _Pragma("unroll") for (int mt = 0; mt < 2; ++mt)                                          \
  _Pragma("unroll") for (int nt = 0; nt < 4; ++nt)                                          \
    acc[mt][nt] = __builtin_amdgcn_mfma_f32_16x16x32_bf16(aF[mt], bF[nt], acc[mt][nt], 0, 0, 0);

  const int nsteps = K >> 5;  // K=1024 or 4096 -> 32 or 128 steps
  STAGE128(0, 0)
  STAGE128(1, 1)
  STAGE128(2, 2)

  int rb = 0, sb = 3;
  for (int t = 0; t < nsteps - 2; ++t) {
    asm volatile("s_waitcnt vmcnt(4)" ::: "memory");
    __builtin_amdgcn_s_barrier();
    __builtin_amdgcn_sched_barrier(0);
    bf16x8 aF[2], bF[4];
    READS128(rb)
    __builtin_amdgcn_sched_barrier(0);
    if (t + 3 < nsteps) { STAGE128(t + 3, sb) }
    __builtin_amdgcn_sched_barrier(0);
    MFMAS128
    rb = (rb + 1 == 4) ? 0 : rb + 1;
    sb = (sb + 1 == 4) ? 0 : sb + 1;
  }
  {  // t = nsteps-2: outstanding tiles {t, t+1} = 4 loads -> wait 2 = tile t
    asm volatile("s_waitcnt vmcnt(2)" ::: "memory");
    __builtin_amdgcn_s_barrier();
    __builtin_amdgcn_sched_barrier(0);
    bf16x8 aF[2], bF[4];
    READS128(rb)
    MFMAS128
    rb = (rb + 1 == 4) ? 0 : rb + 1;
  }
  {  // t = nsteps-1
    asm volatile("s_waitcnt vmcnt(0)" ::: "memory");
    __builtin_amdgcn_s_barrier();
    __builtin_amdgcn_sched_barrier(0);
    bf16x8 aF[2], bF[4];
    READS128(rb)
    MFMAS128
  }
#undef STAGE128
#undef READS128
#undef MFMAS128

  const int fl = (epi == 3) ? *flagp : 0;
  // C/D layout: col = lane&15, row = quad*4 + reg
#pragma unroll
  for (int mt = 0; mt < 2; ++mt) {
#pragma unroll
    for (int nt = 0; nt < 4; ++nt) {
      const int col = n0 + wn * 64 + nt * 16 + m16;
      const float bv = bf2f(bias[col]);
#pragma unroll
      for (int r = 0; r < 4; ++r) {
        const int row = m0 + wm * 32 + mt * 16 + quad * 4 + r;
        const size_t idx = (size_t)row * N + col;
        float v = acc[mt][nt][r] + bv;
        if (epi == 0) {
          outB[idx] = f2bf(v);
        } else if (epi == 1) {
          outB[idx] = f2bf(0.5f * v * (1.0f + erff(v * 0.70710678118654752f)));
        } else if (epi == 2) {
          residOut[idx] = residIn[idx] + v;
        } else {
          const float rr = residIn[idx] + v;
          if (fl) outF[idx] = rr; else outB[idx] = f2bf(rr);
        }
      }
    }
  }
}

// ---------------- GEMM 256x256 (BK=64, swizzled LDS) for big-N GEMMs -------
// (round-17) 8 waves, wave-tile 128x64, acc[8][4]; 2-phase counted schedule.
__global__ __launch_bounds__(512) void gemm256(
    const bf16* __restrict__ A, const bf16* __restrict__ W,
    const bf16* __restrict__ bias, bf16* __restrict__ outB,
    int M, int N, int K, int epi) {
  __shared__ bf16 Abuf[2][256 * 64];
  __shared__ bf16 Bbuf[2][256 * 64];
  const int tid = threadIdx.x;
  const int wave = tid >> 6, lane = tid & 63;
  const int wm = wave >> 2, wn = wave & 3;
  const int quad = lane >> 4, m16 = lane & 15;
  const int m0 = blockIdx.x * 256, n0 = blockIdx.y * 256;
  const int lr8 = lane >> 3, lc8 = lane & 7;
  const int gch = (lc8 ^ lr8) * 8;  // stage-side swizzled k-chunk (elements)
  const int swz = m16 & 7;          // read-side row swizzle key

  f32x4 acc[8][4] = {};

#define STAGE256(T, BUF)                                                         \
  { const int kb_ = (T) * 64 + gch;                                              \
    _Pragma("unroll") for (int i = 0; i < 4; ++i) {                              \
      const int rr = (wave * 4 + i) * 8 + lr8;                                   \
      gload16(A + (size_t)(m0 + rr) * K + kb_, &Abuf[BUF][rr * 64 + lc8 * 8]);   \
      gload16(W + (size_t)(n0 + rr) * K + kb_, &Bbuf[BUF][rr * 64 + lc8 * 8]);   \
    } }

  const int nsteps = K >> 6;  // K=1024 -> 16 steps
  STAGE256(0, 0)
  for (int t = 0; t < nsteps; ++t) {
    asm volatile("s_waitcnt vmcnt(0)" ::: "memory");
    __builtin_amdgcn_s_barrier();
    __builtin_amdgcn_sched_barrier(0);
    const int rb = t & 1;
    bf16x8 aF[2][8], bF[2][4];
#pragma unroll
    for (int kk = 0; kk < 2; ++kk) {
      const int cswz = ((quad + 4 * kk) ^ swz) * 8;
#pragma unroll
      for (int tt = 0; tt < 8; ++tt)
        aF[kk][tt] = *reinterpret_cast<const bf16x8*>(
            &Abuf[rb][(wm * 128 + tt * 16 + m16) * 64 + cswz]);
#pragma unroll
      for (int nt = 0; nt < 4; ++nt)
        bF[kk][nt] = *reinterpret_cast<const bf16x8*>(
            &Bbuf[rb][(wn * 64 + nt * 16 + m16) * 64 + cswz]);
    }
    __builtin_amdgcn_sched_barrier(0);
    if (t + 1 < nsteps) { STAGE256(t + 1, rb ^ 1) }
    __builtin_amdgcn_sched_barrier(0);
#pragma unroll
    for (int kk = 0; kk < 2; ++kk)
#pragma unroll
      for (int mt = 0; mt < 8; ++mt)
#pragma unroll
        for (int nt = 0; nt < 4; ++nt)
          acc[mt][nt] = __builtin_amdgcn_mfma_f32_16x16x32_bf16(
              aF[kk][mt], bF[kk][nt], acc[mt][nt], 0, 0, 0);
  }
#undef STAGE256

  // C/D layout: col = lane&15, row = quad*4 + reg
#pragma unroll
  for (int mt = 0; mt < 8; ++mt) {
#pragma unroll
    for (int nt = 0; nt < 4; ++nt) {
      const int col = n0 + wn * 64 + nt * 16 + m16;
      const float bv = bf2f(bias[col]);
#pragma unroll
      for (int r = 0; r < 4; ++r) {
        const int row = m0 + wm * 128 + mt * 16 + quad * 4 + r;
        const size_t idx = (size_t)row * N + col;
        float v = acc[mt][nt][r] + bv;
        outB[idx] = (epi == 1)
                        ? f2bf(0.5f * v * (1.0f + erff(v * 0.70710678118654752f)))
                        : f2bf(v);
      }
    }
  }
}

// ---------------- RoPE in-place on qkv buffer [4096, 3072] ----------------
__global__ __launch_bounds__(256) void rope_kernel(bf16* __restrict__ qkv,
                                                   const bf16* __restrict__ cosb,
                                                   const bf16* __restrict__ sinb) {
  const int idx = blockIdx.x * 256 + threadIdx.x;  // over 4096*16*32
  const int i = idx & 31;
  const int h = (idx >> 5) & 15;
  const int r = idx >> 9;
  const int s = r & (Ssz - 1);
  const float c = bf2f(cosb[s * 32 + i]);
  const float sn = bf2f(sinb[s * 32 + i]);
  bf16* base = qkv + (size_t)r * (3 * Dm) + h * 64 + 2 * i;
  float x0 = bf2f(base[0]), x1 = bf2f(base[1]);
  base[0] = f2bf(x0 * c - x1 * sn);
  base[1] = f2bf(x0 * sn + x1 * c);
  x0 = bf2f(base[Dm]); x1 = bf2f(base[Dm + 1]);
  base[Dm] = f2bf(x0 * c - x1 * sn);
  base[Dm + 1] = f2bf(x0 * sn + x1 * c);
}

// ---------------- MFMA flash attention: 8 waves, 2 complementary 128-row
// q-tiles per block. qidx = blockIdx.x (half 0), 2*gridDim.x-1-blockIdx.x
// (half 1) -> causal kv-tile count per block is constant (18 at S=1024).
// Inner tile math = round-15 verified code.
__global__ __launch_bounds__(512) void attn_mfma(
    const bf16* __restrict__ Qb, const bf16* __restrict__ Kb, const bf16* __restrict__ Vb,
    bf16* __restrict__ Ob, int qStride, int kvStride, int kvLen, int causal, float scale) {
  __shared__ bf16 Ks[64][72];
  __shared__ bf16 Vt[64][72];
  __shared__ bf16 Ps[128][72];
  const int tid = threadIdx.x;
  const int wave = tid >> 6, lane = tid & 63;
  const int quad = lane >> 4, m16 = lane & 15;
  const int b = blockIdx.z, h = blockIdx.y;

  for (int half = 0; half < 2; ++half) {
    const int qidx = (half == 0) ? blockIdx.x : (2 * gridDim.x - 1 - blockIdx.x);
    const int q0 = qidx * 128;
    __syncthreads();  // Ps reuse guard between halves (uniform)
    {  // Q staging: 512 thr x 32B = 16KB
      const int sr = tid >> 2, sc = (tid & 3) * 16;
      const bf16* qp = Qb + (size_t)(b * Ssz + q0 + sr) * qStride + h * 64 + sc;
      float4 a = reinterpret_cast<const float4*>(qp)[0];
      float4 bb2 = reinterpret_cast<const float4*>(qp)[1];
      *reinterpret_cast<float4*>(&Ps[sr][sc]) = a;
      *reinterpret_cast<float4*>(&Ps[sr][sc + 8]) = bb2;
    }
    __syncthreads();
    bf16x8 qf[2];
    qf[0] = *reinterpret_cast<const bf16x8*>(&Ps[wave * 16 + m16][quad * 8]);
    qf[1] = *reinterpret_cast<const bf16x8*>(&Ps[wave * 16 + m16][32 + quad * 8]);

    f32x4 oacc[4] = {};
    float mrow[4], lrow[4];
#pragma unroll
    for (int r = 0; r < 4; ++r) { mrow[r] = -30000.0f; lrow[r] = 0.0f; }

    const int wrow0 = q0 + wave * 16;  // this wave's first q row
    const int nk = causal ? (q0 + 128) : kvLen;
    for (int kt = 0; kt < nk; kt += 64) {
      {  // K/V staging: row = lane, d-block = 8*wave
        const int dbase = wave * 8;
        const bf16* kp = Kb + (size_t)(b * kvLen + kt + lane) * kvStride + h * 64 + dbase;
        float4 k1 = *reinterpret_cast<const float4*>(kp);
        *reinterpret_cast<float4*>(&Ks[lane][dbase]) = k1;
        const bf16* vp = Vb + (size_t)(b * kvLen + kt + lane) * kvStride + h * 64 + dbase;
        float4 v1 = *reinterpret_cast<const float4*>(vp);
        const bf16* tv = reinterpret_cast<const bf16*>(&v1);
#pragma unroll
        for (int j = 0; j < 8; ++j) Vt[dbase + j][lane] = tv[j];
      }
      __syncthreads();

      const bool live = (causal == 0) || (kt <= wrow0 + 15);
      if (live) {
        f32x4 sacc[4] = {};
#pragma unroll
        for (int nt = 0; nt < 4; ++nt) {
          bf16x8 kf0 = *reinterpret_cast<const bf16x8*>(&Ks[nt * 16 + m16][quad * 8]);
          bf16x8 kf1 = *reinterpret_cast<const bf16x8*>(&Ks[nt * 16 + m16][32 + quad * 8]);
          sacc[nt] = __builtin_amdgcn_mfma_f32_16x16x32_bf16(qf[0], kf0, sacc[nt], 0, 0, 0);
          sacc[nt] = __builtin_amdgcn_mfma_f32_16x16x32_bf16(qf[1], kf1, sacc[nt], 0, 0, 0);
        }
        const bool dmask = (causal != 0) && (kt + 63 > wrow0);
#pragma unroll
        for (int nt = 0; nt < 4; ++nt) {
#pragma unroll
          for (int r = 0; r < 4; ++r) {
            float s = sacc[nt][r] * scale;
            if (dmask && (kt + nt * 16 + m16 > wrow0 + quad * 4 + r)) s = -30000.0f;
            sacc[nt][r] = s;
          }
        }

#pragma unroll
        for (int r = 0; r < 4; ++r) {
          float mx = fmaxf(fmaxf(sacc[0][r], sacc[1][r]), fmaxf(sacc[2][r], sacc[3][r]));
#pragma unroll
          for (int off = 1; off < 16; off <<= 1) mx = fmaxf(mx, __shfl_xor(mx, off));
          const float mn = fmaxf(mrow[r], mx);
          const float corr = __expf(mrow[r] - mn);
          mrow[r] = mn;
          float psum = 0.0f;
#pragma unroll
          for (int nt = 0; nt < 4; ++nt) {
            const float p = __expf(sacc[nt][r] - mn);
            sacc[nt][r] = p;
            psum += p;
          }
#pragma unroll
          for (int off = 1; off < 16; off <<= 1) psum += __shfl_xor(psum, off);
          lrow[r] = lrow[r] * corr + psum;
#pragma unroll
          for (int nt = 0; nt < 4; ++nt) oacc[nt][r] *= corr;
#pragma unroll
          for (int nt = 0; nt < 4; ++nt)
            Ps[wave * 16 + quad * 4 + r][nt * 16 + m16] = f2bf(sacc[nt][r]);
        }
        bf16x8 pf0 = *reinterpret_cast<const bf16x8*>(&Ps[wave * 16 + m16][quad * 8]);
        bf16x8 pf1 = *reinterpret_cast<const bf16x8*>(&Ps[wave * 16 + m16][32 + quad * 8]);
#pragma unroll
        for (int nt = 0; nt < 4; ++nt) {
          bf16x8 vf0 = *reinterpret_cast<const bf16x8*>(&Vt[nt * 16 + m16][quad * 8]);
          bf16x8 vf1 = *reinterpret_cast<const bf16x8*>(&Vt[nt * 16 + m16][32 + quad * 8]);
          oacc[nt] = __builtin_amdgcn_mfma_f32_16x16x32_bf16(pf0, vf0, oacc[nt], 0, 0, 0);
          oacc[nt] = __builtin_amdgcn_mfma_f32_16x16x32_bf16(pf1, vf1, oacc[nt], 0, 0, 0);
        }
      }
      __syncthreads();
    }

    float inv[4];
#pragma unroll
    for (int r = 0; r < 4; ++r) inv[r] = 1.0f / lrow[r];
#pragma unroll
    for (int r = 0; r < 4; ++r) {
      bf16* op = Ob + (size_t)(b * Ssz + q0 + wave * 16 + quad * 4 + r) * Dm + h * 64 + m16;
#pragma unroll
      for (int nt = 0; nt < 4; ++nt) op[nt * 16] = f2bf(oacc[nt][r] * inv[r]);
    }
  }
}

extern "C" void kernel_launch(void* const* d_in, const int* in_sizes, int n_in,
                              void* d_out, int out_size, void* d_ws, size_t ws_size,
                              hipStream_t stream) {
  char* ws = (char*)d_ws;
  int* flagp   = (int*)ws;                          // [0,1MB) control
  float* resid = (float*)(ws + (1ull << 20));       // 16MB fp32 residual
  bf16* xln    = (bf16*)(ws + (17ull << 20));       // 8MB LN output
  bf16* aout   = (bf16*)(ws + (25ull << 20));       // 8MB attn out
  bf16* big    = (bf16*)(ws + (33ull << 20));       // 32MB: qkv | qb | ffn1
  size_t off   = (65ull << 20);                     // canonical bf16 inputs

  detect_kernel<<<1, 64, 0, stream>>>((const unsigned*)d_in[3], flagp);

  CanonArgs ca;
  bf16* c[23];
  for (int i = 0; i < 23; ++i) {
    if (i == 2) { c[i] = nullptr; ca.src[i] = d_in[i]; ca.dst[i] = nullptr; ca.n[i] = 0; continue; }
    c[i] = (bf16*)(ws + off);
    const int n = in_sizes[i];
    off += ((size_t)n * 2 + 255) & ~(size_t)255;
    ca.src[i] = d_in[i];
    ca.dst[i] = c[i];
    ca.n[i] = n;
  }
  canon_all<<<dim3(256, 23), 256, 0, stream>>>(ca, resid, flagp);

  const bf16 *memory = c[1], *rope_cos = c[3], *rope_sin = c[4];
  const bf16 *qkv_w = c[5], *qkv_b = c[6], *out_w = c[7], *out_b = c[8];
  const bf16 *ca_in_w = c[9], *ca_in_b = c[10], *ca_out_w = c[11], *ca_out_b = c[12];
  const bf16 *ffn_w1 = c[13], *ffn_b1 = c[14], *ffn_w2 = c[15], *ffn_b2 = c[16];
  const bf16 *ln1_g = c[17], *ln1_b = c[18], *ln2_g = c[19], *ln2_b = c[20];
  const bf16 *ln3_g = c[21], *ln3_b = c[22];

  bf16* qb = big;
  bf16* kb = (bf16*)(ws + (41ull << 20));
  bf16* vb = (bf16*)(ws + (43ull << 20));
  bf16* outB = (bf16*)d_out;
  float* outF = (float*)d_out;

  const int ROWS = Bn * Ssz;   // 4096
  const float scale = 0.125f;  // 1/sqrt(64)

  // ---- self attention ----
  ln_kernel<<<ROWS, 256, 0, stream>>>(resid, ln1_g, ln1_b, xln);
  gemm256<<<dim3(ROWS / 256, (3 * Dm) / 256), 512, 0, stream>>>(
      xln, qkv_w, qkv_b, big, ROWS, 3 * Dm, Dm, 0);
  rope_kernel<<<(ROWS * Hh * (HDd / 2)) / 256, 256, 0, stream>>>(big, rope_cos, rope_sin);
  attn_mfma<<<dim3(Ssz / 256, Hh, Bn), 512, 0, stream>>>(
      big, big + Dm, big + 2 * Dm, aout, 3 * Dm, 3 * Dm, Ssz, 1, scale);
  gemm128<<<dim3(ROWS / 128, Dm / 128), 512, 0, stream>>>(
      aout, out_w, out_b, nullptr, nullptr, resid, resid, nullptr, ROWS, Dm, Dm, 2);

  // ---- cross attention ----
  ln_kernel<<<ROWS, 256, 0, stream>>>(resid, ln2_g, ln2_b, xln);
  gemm128<<<dim3(ROWS / 128, Dm / 128), 512, 0, stream>>>(
      xln, ca_in_w, ca_in_b, qb, nullptr, nullptr, nullptr, nullptr, ROWS, Dm, Dm, 0);
  gemm_bt<<<dim3((Bn * MEMn) / 64, Dm / 64), 256, 0, stream>>>(
      memory, ca_in_w + (size_t)Dm * Dm, ca_in_b + Dm, kb, nullptr, nullptr, nullptr, nullptr,
      Bn * MEMn, Dm, Dm, 0);
  gemm_bt<<<dim3((Bn * MEMn) / 64, Dm / 64), 256, 0, stream>>>(
      memory, ca_in_w + (size_t)2 * Dm * Dm, ca_in_b + 2 * Dm, vb, nullptr, nullptr, nullptr, nullptr,
      Bn * MEMn, Dm, Dm, 0);
  attn_mfma<<<dim3(Ssz / 256, Hh, Bn), 512, 0, stream>>>(
      qb, kb, vb, aout, Dm, Dm, MEMn, 0, scale);
  gemm128<<<dim3(ROWS / 128, Dm / 128), 512, 0, stream>>>(
      aout, ca_out_w, ca_out_b, nullptr, nullptr, resid, resid, nullptr, ROWS, Dm, Dm, 2);

  // ---- FFN ----
  ln_kernel<<<ROWS, 256, 0, stream>>>(resid, ln3_g, ln3_b, xln);
  gemm256<<<dim3(ROWS / 256, DFFn / 256), 512, 0, stream>>>(
      xln, ffn_w1, ffn_b1, big, ROWS, DFFn, Dm, 1);
  gemm128<<<dim3(ROWS / 128, Dm / 128), 512, 0, stream>>>(
      big, ffn_w2, ffn_b2, outB, outF, resid, nullptr, flagp, ROWS, Dm, DFFn, 3);
}